// Round 1
// baseline (298.006 us; speedup 1.0000x reference)
//
#include <hip/hip_runtime.h>
#include <hip/hip_bf16.h>

// MoE: B=4,T=2048,D=512,E=8,H=512,K=2.  N=8192 tokens.
// Strategy: route first, then compute ONLY the 2 selected experts per token
// (4x FLOP cut vs dense reference), bf16 MFMA for both FFN layers.

typedef __bf16 bf16x8 __attribute__((ext_vector_type(8)));
typedef float  f32x4  __attribute__((ext_vector_type(4)));

#define N_TOK 8192
#define D_IN  512
#define N_EXP 8
#define H_DIM 512
#define TILE  64

static __device__ __forceinline__ unsigned short f2bf(float f) {
    union { float f; unsigned u; } v; v.f = f;
    unsigned r = v.u + 0x7FFFu + ((v.u >> 16) & 1u);   // RNE
    return (unsigned short)(r >> 16);
}

// out[e][j][i] = bf16(in[e][i][j]); 512x512 per expert
__global__ void k_transpose(const float* __restrict__ in, unsigned short* __restrict__ out) {
    __shared__ float tile[32][33];
    int e = blockIdx.z;
    int i0 = blockIdx.y * 32, j0 = blockIdx.x * 32;
    int tx = threadIdx.x, ty = threadIdx.y;
    const float* src = in + (size_t)e * D_IN * H_DIM;
    unsigned short* dst = out + (size_t)e * D_IN * H_DIM;
    #pragma unroll
    for (int r = ty; r < 32; r += 8)
        tile[r][tx] = src[(size_t)(i0 + r) * 512 + j0 + tx];
    __syncthreads();
    #pragma unroll
    for (int r = ty; r < 32; r += 8)
        dst[(size_t)(j0 + r) * 512 + i0 + tx] = f2bf(tile[tx][r]);
}

// f32 gate: logits = x@Wg + bg, top-2 (first-index tie-break like jax top_k),
// softmax over the 2, atomic-append to per-expert token lists.
__global__ void k_gate(const float* __restrict__ x, const float* __restrict__ Wg,
                       const float* __restrict__ bg, int* __restrict__ counts,
                       int* __restrict__ lists, float* __restrict__ wgts) {
    __shared__ float lg[32][8];
    int tid = threadIdx.x;
    int t = tid >> 3, e = tid & 7;
    int n = blockIdx.x * 32 + t;
    const float4* xr = (const float4*)(x + (size_t)n * D_IN);
    float dot = bg[e];
    #pragma unroll 8
    for (int k4 = 0; k4 < 128; ++k4) {
        float4 v = xr[k4];
        int k = k4 * 4;
        dot += v.x * Wg[(k + 0) * 8 + e] + v.y * Wg[(k + 1) * 8 + e]
             + v.z * Wg[(k + 2) * 8 + e] + v.w * Wg[(k + 3) * 8 + e];
    }
    lg[t][e] = dot;
    __syncthreads();
    if (e == 0) {
        float best = lg[t][0]; int i1 = 0;
        #pragma unroll
        for (int j = 1; j < 8; ++j) { float v = lg[t][j]; if (v > best) { best = v; i1 = j; } }
        float best2 = -1e30f; int i2 = 0;
        #pragma unroll
        for (int j = 0; j < 8; ++j) {
            if (j == i1) continue;
            float v = lg[t][j]; if (v > best2) { best2 = v; i2 = j; }
        }
        float tt = expf(best2 - best);
        float w0 = 1.0f / (1.0f + tt), w1 = 1.0f - w0;
        int p0 = atomicAdd(&counts[i1], 1);
        lists[i1 * N_TOK + p0] = n; wgts[i1 * N_TOK + p0] = w0;
        int p1 = atomicAdd(&counts[i2], 1);
        lists[i2 * N_TOK + p1] = n; wgts[i2 * N_TOK + p1] = w1;
    }
}

// Fused 2-layer expert FFN over a gathered 64-token tile.
// Block = 512 thr = 8 waves; wave w owns output cols [w*64, w*64+64).
// LDS: one 64x512 bf16 buffer (64KB), XOR-swizzled, reused X -> H.
__global__ void __launch_bounds__(512, 2)
k_experts(const float* __restrict__ x,
          const unsigned short* __restrict__ w1t, const float* __restrict__ b1,
          const unsigned short* __restrict__ w2t, const float* __restrict__ b2,
          const int* __restrict__ counts, const int* __restrict__ lists,
          const float* __restrict__ wgts, float* __restrict__ out) {
    __shared__ unsigned short lds[TILE * D_IN];   // exactly 64 KiB

    int e = blockIdx.y;
    int tile = blockIdx.x;
    int cnt = counts[e];
    int row0 = tile * TILE;
    if (row0 >= cnt) return;
    int rv = min(TILE, cnt - row0);
    const int*   list_e = lists + e * N_TOK + row0;
    const float* wgt_e  = wgts  + e * N_TOK + row0;

    int tid = threadIdx.x;
    int lane = tid & 63;
    int wid = tid >> 6;
    int cw = wid * 64;
    int l15 = lane & 15, l4 = lane >> 4;

    // ---- stage gathered X tile (f32 -> bf16, swizzled) ----
    #pragma unroll
    for (int it = 0; it < 16; ++it) {
        int idx = tid + it * 512;
        int r = idx >> 7, c4 = idx & 127;
        float4 v = make_float4(0.f, 0.f, 0.f, 0.f);
        if (r < rv) {
            int t = list_e[r];
            v = ((const float4*)(x + (size_t)t * D_IN))[c4];
        }
        unsigned lo = (unsigned)f2bf(v.x) | ((unsigned)f2bf(v.y) << 16);
        unsigned hi = (unsigned)f2bf(v.z) | ((unsigned)f2bf(v.w) << 16);
        int off = (r * 1024 + c4 * 8) ^ ((r & 7) << 4);
        *(uint2*)((char*)lds + off) = make_uint2(lo, hi);
    }
    __syncthreads();

    // ---- stage 1: H = gelu(X @ W1^T + b1) ----
    const unsigned short* w1e = w1t + (size_t)e * D_IN * H_DIM;
    f32x4 acc[4][4];
    #pragma unroll
    for (int n = 0; n < 4; ++n) {
        float bv = b1[e * H_DIM + cw + n * 16 + l15];
        #pragma unroll
        for (int m = 0; m < 4; ++m) acc[m][n] = f32x4{bv, bv, bv, bv};
    }
    #pragma unroll
    for (int kc = 0; kc < 16; ++kc) {
        int k0 = kc * 32 + l4 * 8;
        bf16x8 a[4];
        #pragma unroll
        for (int m = 0; m < 4; ++m) {
            int row = m * 16 + l15;
            int off = (row * 1024 + k0 * 2) ^ ((row & 7) << 4);
            a[m] = *(const bf16x8*)((const char*)lds + off);
        }
        #pragma unroll
        for (int n = 0; n < 4; ++n) {
            int col = cw + n * 16 + l15;
            bf16x8 b = *(const bf16x8*)(w1e + (size_t)col * D_IN + k0);
            #pragma unroll
            for (int m = 0; m < 4; ++m)
                acc[m][n] = __builtin_amdgcn_mfma_f32_16x16x32_bf16(a[m], b, acc[m][n], 0, 0, 0);
        }
    }
    __syncthreads();   // all waves done reading X

    // gelu (exact) + write H back into the same LDS buffer
    #pragma unroll
    for (int m = 0; m < 4; ++m)
        #pragma unroll
        for (int n = 0; n < 4; ++n)
            #pragma unroll
            for (int r = 0; r < 4; ++r) {
                int row = m * 16 + l4 * 4 + r;
                int col = cw + n * 16 + l15;
                float v = acc[m][n][r];
                float g = 0.5f * v * (1.0f + erff(v * 0.70710678118654752f));
                int off = (row * 1024 + col * 2) ^ ((row & 7) << 4);
                *(unsigned short*)((char*)lds + off) = f2bf(g);
            }
    __syncthreads();

    // ---- stage 2: Y = H @ W2^T + b2 ----
    const unsigned short* w2e = w2t + (size_t)e * H_DIM * H_DIM;
    #pragma unroll
    for (int n = 0; n < 4; ++n) {
        float bv = b2[e * H_DIM + cw + n * 16 + l15];
        #pragma unroll
        for (int m = 0; m < 4; ++m) acc[m][n] = f32x4{bv, bv, bv, bv};
    }
    #pragma unroll
    for (int kc = 0; kc < 16; ++kc) {
        int k0 = kc * 32 + l4 * 8;
        bf16x8 a[4];
        #pragma unroll
        for (int m = 0; m < 4; ++m) {
            int row = m * 16 + l15;
            int off = (row * 1024 + k0 * 2) ^ ((row & 7) << 4);
            a[m] = *(const bf16x8*)((const char*)lds + off);
        }
        #pragma unroll
        for (int n = 0; n < 4; ++n) {
            int col = cw + n * 16 + l15;
            bf16x8 b = *(const bf16x8*)(w2e + (size_t)col * H_DIM + k0);
            #pragma unroll
            for (int m = 0; m < 4; ++m)
                acc[m][n] = __builtin_amdgcn_mfma_f32_16x16x32_bf16(a[m], b, acc[m][n], 0, 0, 0);
        }
    }

    // ---- epilogue: out[token] += w * y (each element gets exactly 2 adds) ----
    #pragma unroll
    for (int m = 0; m < 4; ++m) {
        #pragma unroll
        for (int r = 0; r < 4; ++r) {
            int row = m * 16 + l4 * 4 + r;
            if (row < rv) {
                int t = list_e[row];
                float gw = wgt_e[row];
                #pragma unroll
                for (int n = 0; n < 4; ++n) {
                    int col = cw + n * 16 + l15;
                    atomicAdd(out + (size_t)t * H_DIM + col, gw * acc[m][n][r]);
                }
            }
        }
    }
}

extern "C" void kernel_launch(void* const* d_in, const int* in_sizes, int n_in,
                              void* d_out, int out_size, void* d_ws, size_t ws_size,
                              hipStream_t stream) {
    const float* x  = (const float*)d_in[0];
    const float* Wg = (const float*)d_in[1];
    const float* bg = (const float*)d_in[2];
    const float* W1 = (const float*)d_in[3];
    const float* b1 = (const float*)d_in[4];
    const float* W2 = (const float*)d_in[5];
    const float* b2 = (const float*)d_in[6];
    float* out = (float*)d_out;

    char* ws = (char*)d_ws;
    unsigned short* w1t = (unsigned short*)(ws);                 // 4 MiB
    unsigned short* w2t = (unsigned short*)(ws + 4194304);       // 4 MiB
    int*   counts = (int*)(ws + 8388608);                        // 32 B
    int*   lists  = (int*)(ws + 8388864);                        // 256 KiB
    float* wgts   = (float*)(ws + 8651008);                      // 256 KiB

    hipMemsetAsync(out, 0, (size_t)out_size * sizeof(float), stream);
    hipMemsetAsync(counts, 0, N_EXP * sizeof(int), stream);

    k_transpose<<<dim3(16, 16, 8), dim3(32, 8), 0, stream>>>(W1, w1t);
    k_transpose<<<dim3(16, 16, 8), dim3(32, 8), 0, stream>>>(W2, w2t);
    k_gate<<<dim3(N_TOK / 32), dim3(256), 0, stream>>>(x, Wg, bg, counts, lists, wgts);
    k_experts<<<dim3(N_TOK / TILE, N_EXP), dim3(512), 0, stream>>>(
        x, w1t, b1, w2t, b2, counts, lists, wgts, out);
}

// Round 2
// 277.133 us; speedup vs baseline: 1.0753x; 1.0753x over previous
//
#include <hip/hip_runtime.h>
#include <hip/hip_bf16.h>

// MoE: B=4,T=2048,D=512,E=8,H=512,K=2.  N=8192 tokens.
// Route first, compute only the 2 selected experts/token (4x FLOP cut),
// bf16 MFMA for both FFN layers, register-double-buffered B fragments.

typedef __bf16 bf16x8 __attribute__((ext_vector_type(8)));
typedef float  f32x4  __attribute__((ext_vector_type(4)));

#define N_TOK 8192
#define D_IN  512
#define N_EXP 8
#define H_DIM 512
#define TILE  64

static __device__ __forceinline__ unsigned short f2bf(float f) {
    union { float f; unsigned u; } v; v.f = f;
    unsigned r = v.u + 0x7FFFu + ((v.u >> 16) & 1u);   // RNE
    return (unsigned short)(r >> 16);
}

// out[e][j][i] = bf16(in[e][i][j]); 512x512 per expert
__global__ void k_transpose(const float* __restrict__ in, unsigned short* __restrict__ out) {
    __shared__ float tile[32][33];
    int e = blockIdx.z;
    int i0 = blockIdx.y * 32, j0 = blockIdx.x * 32;
    int tx = threadIdx.x, ty = threadIdx.y;
    const float* src = in + (size_t)e * D_IN * H_DIM;
    unsigned short* dst = out + (size_t)e * D_IN * H_DIM;
    #pragma unroll
    for (int r = ty; r < 32; r += 8)
        tile[r][tx] = src[(size_t)(i0 + r) * 512 + j0 + tx];
    __syncthreads();
    #pragma unroll
    for (int r = ty; r < 32; r += 8)
        dst[(size_t)(j0 + r) * 512 + i0 + tx] = f2bf(tile[tx][r]);
}

// Gate: per-token top-2 (first-index tie-break like jax top_k) + softmax.
// NO atomics — writes sel[n] (packed expert ids) and w2[n] (weights).
__global__ void k_gate(const float* __restrict__ x, const float* __restrict__ Wg,
                       const float* __restrict__ bg,
                       unsigned char* __restrict__ sel, float2* __restrict__ w2) {
    __shared__ float lg[32][9];
    int tid = threadIdx.x;
    int t = tid >> 3, e = tid & 7;
    int n = blockIdx.x * 32 + t;
    const float4* xr = (const float4*)(x + (size_t)n * D_IN);
    float dot = bg[e];
    #pragma unroll 8
    for (int k4 = 0; k4 < 128; ++k4) {
        float4 v = xr[k4];
        int k = k4 * 4;
        dot += v.x * Wg[(k + 0) * 8 + e] + v.y * Wg[(k + 1) * 8 + e]
             + v.z * Wg[(k + 2) * 8 + e] + v.w * Wg[(k + 3) * 8 + e];
    }
    lg[t][e] = dot;
    __syncthreads();
    if (e == 0) {
        float best = lg[t][0]; int i1 = 0;
        #pragma unroll
        for (int j = 1; j < 8; ++j) { float v = lg[t][j]; if (v > best) { best = v; i1 = j; } }
        float best2 = -1e30f; int i2 = 0;
        #pragma unroll
        for (int j = 0; j < 8; ++j) {
            if (j == i1) continue;
            float v = lg[t][j]; if (v > best2) { best2 = v; i2 = j; }
        }
        float tt = expf(best2 - best);
        float w0 = 1.0f / (1.0f + tt);
        sel[n] = (unsigned char)(i1 | (i2 << 4));
        w2[n] = make_float2(w0, 1.0f - w0);
    }
}

// Build per-expert compacted token lists, deterministic ballot/prefix scan.
// 8 blocks (one per expert), 256 threads each. No global atomics.
__global__ void __launch_bounds__(256) k_build(const unsigned char* __restrict__ sel,
                                               const float2* __restrict__ w2,
                                               int* __restrict__ counts,
                                               int* __restrict__ lists,
                                               float* __restrict__ wgts) {
    int e = blockIdx.x;
    __shared__ int wave_tot[4];
    int tid = threadIdx.x;
    int lane = tid & 63, wv = tid >> 6;
    int base = 0;
    for (int c0 = 0; c0 < N_TOK; c0 += 256) {
        int n = c0 + tid;
        unsigned char s = sel[n];
        int i1 = s & 15, i2 = s >> 4;
        bool f1 = (i1 == e);
        bool f = f1 || (i2 == e);
        unsigned long long mask = __ballot(f);
        int prefix = __popcll(mask & ((1ull << lane) - 1ull));
        if (lane == 0) wave_tot[wv] = __popcll(mask);
        __syncthreads();
        int wbase = 0;
        #pragma unroll
        for (int i = 0; i < 4; ++i) if (i < wv) wbase += wave_tot[i];
        if (f) {
            int pos = base + wbase + prefix;
            lists[e * N_TOK + pos] = n;
            float2 w = w2[n];
            wgts[e * N_TOK + pos] = f1 ? w.x : w.y;
        }
        base += wave_tot[0] + wave_tot[1] + wave_tot[2] + wave_tot[3];
        __syncthreads();
    }
    if (tid == 0) counts[e] = base;
}

// Fused 2-layer expert FFN over a gathered 64-token tile.
// Block = 512 thr = 8 waves; wave w owns output cols [w*64, w*64+64).
// LDS: one 64x512 bf16 buffer (64KB), XOR-swizzled, reused X -> H.
// B fragments register-double-buffered (prefetch kc+1 before kc's MFMAs).
__global__ void __launch_bounds__(512)
k_experts(const float* __restrict__ x,
          const unsigned short* __restrict__ w1t, const float* __restrict__ b1,
          const unsigned short* __restrict__ w2t, const float* __restrict__ b2,
          const int* __restrict__ counts, const int* __restrict__ lists,
          const float* __restrict__ wgts, float* __restrict__ out) {
    __shared__ unsigned short lds[TILE * D_IN];   // exactly 64 KiB

    int e = blockIdx.y;
    int tile = blockIdx.x;
    int cnt = counts[e];
    int row0 = tile * TILE;
    if (row0 >= cnt) return;
    int rv = min(TILE, cnt - row0);
    const int*   list_e = lists + e * N_TOK + row0;
    const float* wgt_e  = wgts  + e * N_TOK + row0;

    int tid = threadIdx.x;
    int lane = tid & 63;
    int wid = tid >> 6;
    int cw = wid * 64;
    int l15 = lane & 15, l4 = lane >> 4;

    // ---- stage gathered X tile (f32 -> bf16, swizzled) ----
    #pragma unroll
    for (int it = 0; it < 16; ++it) {
        int idx = tid + it * 512;
        int r = idx >> 7, c4 = idx & 127;
        float4 v = make_float4(0.f, 0.f, 0.f, 0.f);
        if (r < rv) {
            int t = list_e[r];
            v = ((const float4*)(x + (size_t)t * D_IN))[c4];
        }
        unsigned lo = (unsigned)f2bf(v.x) | ((unsigned)f2bf(v.y) << 16);
        unsigned hi = (unsigned)f2bf(v.z) | ((unsigned)f2bf(v.w) << 16);
        int off = (r * 1024 + c4 * 8) ^ ((r & 7) << 4);
        *(uint2*)((char*)lds + off) = make_uint2(lo, hi);
    }
    __syncthreads();

    // ---- stage 1: H = gelu(X @ W1^T + b1) ----
    const unsigned short* w1e = w1t + (size_t)e * D_IN * H_DIM;
    f32x4 acc[4][4];
    #pragma unroll
    for (int n = 0; n < 4; ++n) {
        float bv = b1[e * H_DIM + cw + n * 16 + l15];
        #pragma unroll
        for (int m = 0; m < 4; ++m) acc[m][n] = f32x4{bv, bv, bv, bv};
    }
    {
        bf16x8 bcur[4], bnxt[4];
        #pragma unroll
        for (int n = 0; n < 4; ++n)
            bcur[n] = *(const bf16x8*)(w1e + (size_t)(cw + n * 16 + l15) * D_IN + l4 * 8);
        #pragma unroll
        for (int kc = 0; kc < 16; ++kc) {
            int k0 = kc * 32 + l4 * 8;
            if (kc < 15) {
                #pragma unroll
                for (int n = 0; n < 4; ++n)
                    bnxt[n] = *(const bf16x8*)(w1e + (size_t)(cw + n * 16 + l15) * D_IN + k0 + 32);
            }
            bf16x8 a[4];
            #pragma unroll
            for (int m = 0; m < 4; ++m) {
                int row = m * 16 + l15;
                int off = (row * 1024 + k0 * 2) ^ ((row & 7) << 4);
                a[m] = *(const bf16x8*)((const char*)lds + off);
            }
            #pragma unroll
            for (int n = 0; n < 4; ++n)
                #pragma unroll
                for (int m = 0; m < 4; ++m)
                    acc[m][n] = __builtin_amdgcn_mfma_f32_16x16x32_bf16(a[m], bcur[n], acc[m][n], 0, 0, 0);
            #pragma unroll
            for (int n = 0; n < 4; ++n) bcur[n] = bnxt[n];
        }
    }
    __syncthreads();   // all waves done reading X

    // gelu (exact) + write H back into the same LDS buffer
    #pragma unroll
    for (int m = 0; m < 4; ++m)
        #pragma unroll
        for (int n = 0; n < 4; ++n)
            #pragma unroll
            for (int r = 0; r < 4; ++r) {
                int row = m * 16 + l4 * 4 + r;
                int col = cw + n * 16 + l15;
                float v = acc[m][n][r];
                float g = 0.5f * v * (1.0f + erff(v * 0.70710678118654752f));
                int off = (row * 1024 + col * 2) ^ ((row & 7) << 4);
                *(unsigned short*)((char*)lds + off) = f2bf(g);
            }
    __syncthreads();

    // ---- stage 2: Y = H @ W2^T + b2 ----
    const unsigned short* w2e = w2t + (size_t)e * H_DIM * H_DIM;
    #pragma unroll
    for (int n = 0; n < 4; ++n) {
        float bv = b2[e * H_DIM + cw + n * 16 + l15];
        #pragma unroll
        for (int m = 0; m < 4; ++m) acc[m][n] = f32x4{bv, bv, bv, bv};
    }
    {
        bf16x8 bcur[4], bnxt[4];
        #pragma unroll
        for (int n = 0; n < 4; ++n)
            bcur[n] = *(const bf16x8*)(w2e + (size_t)(cw + n * 16 + l15) * H_DIM + l4 * 8);
        #pragma unroll
        for (int kc = 0; kc < 16; ++kc) {
            int k0 = kc * 32 + l4 * 8;
            if (kc < 15) {
                #pragma unroll
                for (int n = 0; n < 4; ++n)
                    bnxt[n] = *(const bf16x8*)(w2e + (size_t)(cw + n * 16 + l15) * H_DIM + k0 + 32);
            }
            bf16x8 a[4];
            #pragma unroll
            for (int m = 0; m < 4; ++m) {
                int row = m * 16 + l15;
                int off = (row * 1024 + k0 * 2) ^ ((row & 7) << 4);
                a[m] = *(const bf16x8*)((const char*)lds + off);
            }
            #pragma unroll
            for (int n = 0; n < 4; ++n)
                #pragma unroll
                for (int m = 0; m < 4; ++m)
                    acc[m][n] = __builtin_amdgcn_mfma_f32_16x16x32_bf16(a[m], bcur[n], acc[m][n], 0, 0, 0);
            #pragma unroll
            for (int n = 0; n < 4; ++n) bcur[n] = bnxt[n];
        }
    }

    // ---- epilogue: out[token] += w * y (each element gets exactly 2 adds) ----
    #pragma unroll
    for (int m = 0; m < 4; ++m) {
        #pragma unroll
        for (int r = 0; r < 4; ++r) {
            int row = m * 16 + l4 * 4 + r;
            if (row < rv) {
                int t = list_e[row];
                float gw = wgt_e[row];
                #pragma unroll
                for (int n = 0; n < 4; ++n) {
                    int col = cw + n * 16 + l15;
                    atomicAdd(out + (size_t)t * H_DIM + col, gw * acc[m][n][r]);
                }
            }
        }
    }
}

extern "C" void kernel_launch(void* const* d_in, const int* in_sizes, int n_in,
                              void* d_out, int out_size, void* d_ws, size_t ws_size,
                              hipStream_t stream) {
    const float* x  = (const float*)d_in[0];
    const float* Wg = (const float*)d_in[1];
    const float* bg = (const float*)d_in[2];
    const float* W1 = (const float*)d_in[3];
    const float* b1 = (const float*)d_in[4];
    const float* W2 = (const float*)d_in[5];
    const float* b2 = (const float*)d_in[6];
    float* out = (float*)d_out;

    char* ws = (char*)d_ws;
    unsigned short* w1t = (unsigned short*)(ws);                 // 4 MiB
    unsigned short* w2t = (unsigned short*)(ws + 4194304);       // 4 MiB
    int*   counts = (int*)(ws + 8388608);                        // 32 B
    int*   lists  = (int*)(ws + 8388864);                        // 256 KiB
    float* wgts   = (float*)(ws + 8651008);                      // 256 KiB
    unsigned char* sel = (unsigned char*)(ws + 8913152);         // 8 KiB
    float2* w2g   = (float2*)(ws + 8921344);                     // 64 KiB

    hipMemsetAsync(out, 0, (size_t)out_size * sizeof(float), stream);

    k_transpose<<<dim3(16, 16, 8), dim3(32, 8), 0, stream>>>(W1, w1t);
    k_transpose<<<dim3(16, 16, 8), dim3(32, 8), 0, stream>>>(W2, w2t);
    k_gate<<<dim3(N_TOK / 32), dim3(256), 0, stream>>>(x, Wg, bg, sel, w2g);
    k_build<<<dim3(N_EXP), dim3(256), 0, stream>>>(sel, w2g, counts, lists, wgts);
    k_experts<<<dim3(N_TOK / TILE, N_EXP), dim3(512), 0, stream>>>(
        x, w1t, b1, w2t, b2, counts, lists, wgts, out);
}

// Round 3
// 237.350 us; speedup vs baseline: 1.2556x; 1.1676x over previous
//
#include <hip/hip_runtime.h>
#include <hip/hip_bf16.h>

// MoE: B=4,T=2048,D=512,E=8,H=512,K=2.  N=8192 tokens.
// Route, then compute only the 2 selected experts/token.  bf16 MFMA.
// v3: expert->XCD affinity (e = blockIdx&7), fragment-packed weights
// (coalesced B loads), depth-2 register prefetch, wide k_build.

typedef __bf16 bf16x8 __attribute__((ext_vector_type(8)));
typedef float  f32x4  __attribute__((ext_vector_type(4)));

#define N_TOK 8192
#define D_IN  512
#define N_EXP 8
#define H_DIM 512
#define TILE  64

static __device__ __forceinline__ unsigned short f2bf(float f) {
    union { float f; unsigned u; } v; v.f = f;
    unsigned r = v.u + 0x7FFFu + ((v.u >> 16) & 1u);   // RNE
    return (unsigned short)(r >> 16);
}

// Pack W (f32 [E][512k][512c]) into MFMA B-fragment-linear bf16 layout:
// out[((e*32 + cb)*16 + kc)*512 + lane*8 + j] = bf16(W[e][kc*32+(lane>>4)*8+j][cb*16+(lane&15)])
// One block handles (e, kc, 64 cols) = a 32x64 f32 tile.
__global__ void __launch_bounds__(256) k_pack(const float* __restrict__ in,
                                              unsigned short* __restrict__ out) {
    __shared__ float t[32][65];
    int cb0 = blockIdx.x * 4;          // 4 col-blocks of 16
    int kc  = blockIdx.y;              // 0..15
    int e   = blockIdx.z;              // 0..7
    const float* src = in + ((size_t)e * 512 + kc * 32) * 512 + blockIdx.x * 64;
    int tid = threadIdx.x;
    int r = tid >> 3, cq = (tid & 7) * 8;
    float4 v0 = *(const float4*)(src + (size_t)r * 512 + cq);
    float4 v1 = *(const float4*)(src + (size_t)r * 512 + cq + 4);
    t[r][cq + 0] = v0.x; t[r][cq + 1] = v0.y; t[r][cq + 2] = v0.z; t[r][cq + 3] = v0.w;
    t[r][cq + 4] = v1.x; t[r][cq + 5] = v1.y; t[r][cq + 6] = v1.z; t[r][cq + 7] = v1.w;
    __syncthreads();
    int g = tid >> 6, lane = tid & 63;
    int l15 = lane & 15, l4 = lane >> 4;
    unsigned v[4];
    #pragma unroll
    for (int j = 0; j < 4; ++j) {
        unsigned lo = f2bf(t[l4 * 8 + 2 * j    ][g * 16 + l15]);
        unsigned hi = f2bf(t[l4 * 8 + 2 * j + 1][g * 16 + l15]);
        v[j] = lo | (hi << 16);
    }
    size_t dst = (((size_t)(e * 32 + cb0 + g) * 16 + kc) * 512) + lane * 8;
    *(uint4*)(out + dst) = make_uint4(v[0], v[1], v[2], v[3]);
}

// Gate: per-token top-2 (first-index tie-break like jax top_k) + softmax.
__global__ void k_gate(const float* __restrict__ x, const float* __restrict__ Wg,
                       const float* __restrict__ bg,
                       unsigned char* __restrict__ sel, float2* __restrict__ w2) {
    __shared__ float lg[32][9];
    int tid = threadIdx.x;
    int t = tid >> 3, e = tid & 7;
    int n = blockIdx.x * 32 + t;
    const float4* xr = (const float4*)(x + (size_t)n * D_IN);
    float dot = bg[e];
    #pragma unroll 8
    for (int k4 = 0; k4 < 128; ++k4) {
        float4 v = xr[k4];
        int k = k4 * 4;
        dot += v.x * Wg[(k + 0) * 8 + e] + v.y * Wg[(k + 1) * 8 + e]
             + v.z * Wg[(k + 2) * 8 + e] + v.w * Wg[(k + 3) * 8 + e];
    }
    lg[t][e] = dot;
    __syncthreads();
    if (e == 0) {
        float best = lg[t][0]; int i1 = 0;
        #pragma unroll
        for (int j = 1; j < 8; ++j) { float v = lg[t][j]; if (v > best) { best = v; i1 = j; } }
        float best2 = -1e30f; int i2 = 0;
        #pragma unroll
        for (int j = 0; j < 8; ++j) {
            if (j == i1) continue;
            float v = lg[t][j]; if (v > best2) { best2 = v; i2 = j; }
        }
        float tt = expf(best2 - best);
        float w0 = 1.0f / (1.0f + tt);
        sel[n] = (unsigned char)(i1 | (i2 << 4));
        w2[n] = make_float2(w0, 1.0f - w0);
    }
}

// Build per-expert compacted token lists; deterministic ballot/prefix scan.
// 8 blocks x 1024 threads -> 8 scan iterations.
__global__ void __launch_bounds__(1024) k_build(const unsigned char* __restrict__ sel,
                                                const float2* __restrict__ w2,
                                                int* __restrict__ counts,
                                                int* __restrict__ lists,
                                                float* __restrict__ wgts) {
    int e = blockIdx.x;
    __shared__ int wave_tot[16], wave_base[16];
    int tid = threadIdx.x;
    int lane = tid & 63, wv = tid >> 6;
    int base = 0;
    for (int c0 = 0; c0 < N_TOK; c0 += 1024) {
        int n = c0 + tid;
        unsigned char s = sel[n];
        bool f1 = ((s & 15) == e);
        bool f = f1 || ((s >> 4) == e);
        unsigned long long mask = __ballot(f);
        int prefix = __popcll(mask & ((1ull << lane) - 1ull));
        if (lane == 0) wave_tot[wv] = __popcll(mask);
        __syncthreads();
        if (tid < 16) {
            int wb = 0;
            for (int i = 0; i < tid; ++i) wb += wave_tot[i];
            wave_base[tid] = wb;
        }
        __syncthreads();
        if (f) {
            int pos = base + wave_base[wv] + prefix;
            lists[e * N_TOK + pos] = n;
            float2 w = w2[n];
            wgts[e * N_TOK + pos] = f1 ? w.x : w.y;
        }
        base += wave_base[15] + wave_tot[15];
        __syncthreads();
    }
    if (tid == 0) counts[e] = base;
}

// Fused 2-layer expert FFN over a gathered 64-token tile.
// Flat grid: e = blockIdx&7 (-> XCD e), tile = blockIdx>>3.
// Block = 512 thr = 8 waves; wave w owns output cols [w*64, w*64+64).
// LDS: one 64x512 bf16 buffer (64KB), XOR-swizzled, reused X -> H.
// B fragments: packed layout, coalesced 16B/lane, depth-2 prefetch.
__global__ void __launch_bounds__(512, 1)
k_experts(const float* __restrict__ x,
          const unsigned short* __restrict__ w1f, const float* __restrict__ b1,
          const unsigned short* __restrict__ w2f, const float* __restrict__ b2,
          const int* __restrict__ counts, const int* __restrict__ lists,
          const float* __restrict__ wgts, float* __restrict__ out) {
    __shared__ unsigned short lds[TILE * D_IN];   // exactly 64 KiB

    int b = blockIdx.x;
    int e = b & 7;                 // expert -> XCD affinity (round-robin % 8)
    int tile = b >> 3;
    int cnt = counts[e];
    int row0 = tile * TILE;
    if (row0 >= cnt) return;
    int rv = min(TILE, cnt - row0);
    const int*   list_e = lists + e * N_TOK + row0;
    const float* wgt_e  = wgts  + e * N_TOK + row0;

    int tid = threadIdx.x;
    int lane = tid & 63;
    int wid = tid >> 6;
    int cw = wid * 64;
    int l15 = lane & 15, l4 = lane >> 4;

    // ---- stage gathered X tile (f32 -> bf16, swizzled) ----
    #pragma unroll
    for (int it = 0; it < 16; ++it) {
        int idx = tid + it * 512;
        int r = idx >> 7, c4 = idx & 127;
        float4 v = make_float4(0.f, 0.f, 0.f, 0.f);
        if (r < rv) {
            int t = list_e[r];
            v = ((const float4*)(x + (size_t)t * D_IN))[c4];
        }
        unsigned lo = (unsigned)f2bf(v.x) | ((unsigned)f2bf(v.y) << 16);
        unsigned hi = (unsigned)f2bf(v.z) | ((unsigned)f2bf(v.w) << 16);
        int off = (r * 1024 + c4 * 8) ^ ((r & 7) << 4);
        *(uint2*)((char*)lds + off) = make_uint2(lo, hi);
    }
    __syncthreads();

    // ---- stage 1: H = gelu(X @ W1^T + b1) ----
    // packed frag base: frag(n, kc) at w1base + (n*16 + kc)*512 elements
    const unsigned short* w1base = w1f + ((size_t)(e * 32 + wid * 4) * 16) * 512 + (size_t)lane * 8;
    f32x4 acc[4][4];
    #pragma unroll
    for (int n = 0; n < 4; ++n) {
        float bv = b1[e * H_DIM + cw + n * 16 + l15];
        #pragma unroll
        for (int m = 0; m < 4; ++m) acc[m][n] = f32x4{bv, bv, bv, bv};
    }
    {
        bf16x8 bb[3][4];
        #pragma unroll
        for (int n = 0; n < 4; ++n) {
            bb[0][n] = *(const bf16x8*)(w1base + (n * 16 + 0) * 512);
            bb[1][n] = *(const bf16x8*)(w1base + (n * 16 + 1) * 512);
        }
        #pragma unroll
        for (int kc = 0; kc < 16; ++kc) {
            if (kc + 2 < 16) {
                #pragma unroll
                for (int n = 0; n < 4; ++n)
                    bb[(kc + 2) % 3][n] = *(const bf16x8*)(w1base + (n * 16 + kc + 2) * 512);
            }
            int k0 = kc * 32 + l4 * 8;
            bf16x8 a[4];
            #pragma unroll
            for (int m = 0; m < 4; ++m) {
                int row = m * 16 + l15;
                int off = (row * 1024 + k0 * 2) ^ ((row & 7) << 4);
                a[m] = *(const bf16x8*)((const char*)lds + off);
            }
            #pragma unroll
            for (int n = 0; n < 4; ++n)
                #pragma unroll
                for (int m = 0; m < 4; ++m)
                    acc[m][n] = __builtin_amdgcn_mfma_f32_16x16x32_bf16(a[m], bb[kc % 3][n], acc[m][n], 0, 0, 0);
        }
    }
    __syncthreads();   // all waves done reading X

    // gelu (exact) + write H back into the same LDS buffer
    #pragma unroll
    for (int m = 0; m < 4; ++m)
        #pragma unroll
        for (int n = 0; n < 4; ++n)
            #pragma unroll
            for (int r = 0; r < 4; ++r) {
                int row = m * 16 + l4 * 4 + r;
                int col = cw + n * 16 + l15;
                float v = acc[m][n][r];
                float g = 0.5f * v * (1.0f + erff(v * 0.70710678118654752f));
                int off = (row * 1024 + col * 2) ^ ((row & 7) << 4);
                *(unsigned short*)((char*)lds + off) = f2bf(g);
            }
    __syncthreads();

    // ---- stage 2: Y = H @ W2^T + b2 ----
    const unsigned short* w2base = w2f + ((size_t)(e * 32 + wid * 4) * 16) * 512 + (size_t)lane * 8;
    #pragma unroll
    for (int n = 0; n < 4; ++n) {
        float bv = b2[e * H_DIM + cw + n * 16 + l15];
        #pragma unroll
        for (int m = 0; m < 4; ++m) acc[m][n] = f32x4{bv, bv, bv, bv};
    }
    {
        bf16x8 bb[3][4];
        #pragma unroll
        for (int n = 0; n < 4; ++n) {
            bb[0][n] = *(const bf16x8*)(w2base + (n * 16 + 0) * 512);
            bb[1][n] = *(const bf16x8*)(w2base + (n * 16 + 1) * 512);
        }
        #pragma unroll
        for (int kc = 0; kc < 16; ++kc) {
            if (kc + 2 < 16) {
                #pragma unroll
                for (int n = 0; n < 4; ++n)
                    bb[(kc + 2) % 3][n] = *(const bf16x8*)(w2base + (n * 16 + kc + 2) * 512);
            }
            int k0 = kc * 32 + l4 * 8;
            bf16x8 a[4];
            #pragma unroll
            for (int m = 0; m < 4; ++m) {
                int row = m * 16 + l15;
                int off = (row * 1024 + k0 * 2) ^ ((row & 7) << 4);
                a[m] = *(const bf16x8*)((const char*)lds + off);
            }
            #pragma unroll
            for (int n = 0; n < 4; ++n)
                #pragma unroll
                for (int m = 0; m < 4; ++m)
                    acc[m][n] = __builtin_amdgcn_mfma_f32_16x16x32_bf16(a[m], bb[kc % 3][n], acc[m][n], 0, 0, 0);
        }
    }

    // ---- epilogue: out[token] += w * y (each element gets exactly 2 adds) ----
    #pragma unroll
    for (int m = 0; m < 4; ++m) {
        #pragma unroll
        for (int r = 0; r < 4; ++r) {
            int row = m * 16 + l4 * 4 + r;
            if (row < rv) {
                int t = list_e[row];
                float gw = wgt_e[row];
                #pragma unroll
                for (int n = 0; n < 4; ++n) {
                    int col = cw + n * 16 + l15;
                    atomicAdd(out + (size_t)t * H_DIM + col, gw * acc[m][n][r]);
                }
            }
        }
    }
}

extern "C" void kernel_launch(void* const* d_in, const int* in_sizes, int n_in,
                              void* d_out, int out_size, void* d_ws, size_t ws_size,
                              hipStream_t stream) {
    const float* x  = (const float*)d_in[0];
    const float* Wg = (const float*)d_in[1];
    const float* bg = (const float*)d_in[2];
    const float* W1 = (const float*)d_in[3];
    const float* b1 = (const float*)d_in[4];
    const float* W2 = (const float*)d_in[5];
    const float* b2 = (const float*)d_in[6];
    float* out = (float*)d_out;

    char* ws = (char*)d_ws;
    unsigned short* w1f = (unsigned short*)(ws);                 // 4 MiB
    unsigned short* w2f = (unsigned short*)(ws + 4194304);       // 4 MiB
    int*   counts = (int*)(ws + 8388608);                        // 32 B
    int*   lists  = (int*)(ws + 8388864);                        // 256 KiB
    float* wgts   = (float*)(ws + 8651008);                      // 256 KiB
    unsigned char* sel = (unsigned char*)(ws + 8913152);         // 8 KiB
    float2* w2g   = (float2*)(ws + 8921344);                     // 64 KiB

    hipMemsetAsync(out, 0, (size_t)out_size * sizeof(float), stream);

    k_pack<<<dim3(8, 16, 8), dim3(256), 0, stream>>>(W1, w1f);
    k_pack<<<dim3(8, 16, 8), dim3(256), 0, stream>>>(W2, w2f);
    k_gate<<<dim3(N_TOK / 32), dim3(256), 0, stream>>>(x, Wg, bg, sel, w2g);
    k_build<<<dim3(N_EXP), dim3(1024), 0, stream>>>(sel, w2g, counts, lists, wgts);
    k_experts<<<dim3(1024), dim3(512), 0, stream>>>(
        x, w1f, b1, w2f, b2, counts, lists, wgts, out);
}

// Round 4
// 214.181 us; speedup vs baseline: 1.3914x; 1.1082x over previous
//
#include <hip/hip_runtime.h>
#include <hip/hip_bf16.h>

// MoE: B=4,T=2048,D=512,E=8,H=512,K=2.  N=8192 tokens.
// v4: TILE=32 (2 blocks/CU co-resident), slot-based ybuf + combine kernel
// (no output atomics), merged pack launch, no memset node.

typedef __bf16 bf16x8 __attribute__((ext_vector_type(8)));
typedef float  f32x4  __attribute__((ext_vector_type(4)));

#define N_TOK 8192
#define D_IN  512
#define N_EXP 8
#define H_DIM 512
#define TILE  32

static __device__ __forceinline__ unsigned short f2bf(float f) {
    union { float f; unsigned u; } v; v.f = f;
    unsigned r = v.u + 0x7FFFu + ((v.u >> 16) & 1u);   // RNE
    return (unsigned short)(r >> 16);
}
static __device__ __forceinline__ float bf2f(unsigned short h) {
    union { unsigned u; float f; } v; v.u = ((unsigned)h) << 16; return v.f;
}

// Pack W1 and W2 (f32 [E][512][512]) into MFMA B-fragment-linear bf16:
// out[((e*32+cb)*16+kc)*512 + lane*8 + j] = bf16(W[e][kc*32+(lane>>4)*8+j][cb*16+(lane&15)])
// blockIdx.z 0..15: z<8 -> W1 expert z ; z>=8 -> W2 expert z-8.
__global__ void __launch_bounds__(256) k_pack(const float* __restrict__ W1,
                                              const float* __restrict__ W2,
                                              unsigned short* __restrict__ w1f,
                                              unsigned short* __restrict__ w2f) {
    __shared__ float t[32][65];
    int z = blockIdx.z;
    int e = z & 7;
    const float* in = (z < 8) ? W1 : W2;
    unsigned short* out = (z < 8) ? w1f : w2f;
    int cb0 = blockIdx.x * 4;          // 4 col-blocks of 16
    int kc  = blockIdx.y;              // 0..15
    const float* src = in + ((size_t)e * 512 + kc * 32) * 512 + blockIdx.x * 64;
    int tid = threadIdx.x;
    int r = tid >> 3, cq = (tid & 7) * 8;
    float4 v0 = *(const float4*)(src + (size_t)r * 512 + cq);
    float4 v1 = *(const float4*)(src + (size_t)r * 512 + cq + 4);
    t[r][cq + 0] = v0.x; t[r][cq + 1] = v0.y; t[r][cq + 2] = v0.z; t[r][cq + 3] = v0.w;
    t[r][cq + 4] = v1.x; t[r][cq + 5] = v1.y; t[r][cq + 6] = v1.z; t[r][cq + 7] = v1.w;
    __syncthreads();
    int g = tid >> 6, lane = tid & 63;
    int l15 = lane & 15, l4 = lane >> 4;
    unsigned v[4];
    #pragma unroll
    for (int j = 0; j < 4; ++j) {
        unsigned lo = f2bf(t[l4 * 8 + 2 * j    ][g * 16 + l15]);
        unsigned hi = f2bf(t[l4 * 8 + 2 * j + 1][g * 16 + l15]);
        v[j] = lo | (hi << 16);
    }
    size_t dst = (((size_t)(e * 32 + cb0 + g) * 16 + kc) * 512) + lane * 8;
    *(uint4*)(out + dst) = make_uint4(v[0], v[1], v[2], v[3]);
}

// Gate: per-token top-2 (first-index tie-break like jax top_k) + softmax.
__global__ void k_gate(const float* __restrict__ x, const float* __restrict__ Wg,
                       const float* __restrict__ bg,
                       unsigned char* __restrict__ sel, float2* __restrict__ w2) {
    __shared__ float lg[32][9];
    int tid = threadIdx.x;
    int t = tid >> 3, e = tid & 7;
    int n = blockIdx.x * 32 + t;
    const float4* xr = (const float4*)(x + (size_t)n * D_IN);
    float dot = bg[e];
    #pragma unroll 8
    for (int k4 = 0; k4 < 128; ++k4) {
        float4 v = xr[k4];
        int k = k4 * 4;
        dot += v.x * Wg[(k + 0) * 8 + e] + v.y * Wg[(k + 1) * 8 + e]
             + v.z * Wg[(k + 2) * 8 + e] + v.w * Wg[(k + 3) * 8 + e];
    }
    lg[t][e] = dot;
    __syncthreads();
    if (e == 0) {
        float best = lg[t][0]; int i1 = 0;
        #pragma unroll
        for (int j = 1; j < 8; ++j) { float v = lg[t][j]; if (v > best) { best = v; i1 = j; } }
        float best2 = -1e30f; int i2 = 0;
        #pragma unroll
        for (int j = 0; j < 8; ++j) {
            if (j == i1) continue;
            float v = lg[t][j]; if (v > best2) { best2 = v; i2 = j; }
        }
        float tt = expf(best2 - best);
        float w0 = 1.0f / (1.0f + tt);
        sel[n] = (unsigned char)(i1 | (i2 << 4));
        w2[n] = make_float2(w0, 1.0f - w0);
    }
}

// Build per-expert compacted token lists; deterministic ballot/prefix scan.
// lists entry = (token<<1) | slot  (slot 0 = top1, 1 = top2).
__global__ void __launch_bounds__(1024) k_build(const unsigned char* __restrict__ sel,
                                                const float2* __restrict__ w2,
                                                int* __restrict__ counts,
                                                int* __restrict__ lists,
                                                float* __restrict__ wgts) {
    int e = blockIdx.x;
    __shared__ int wave_tot[16], wave_base[16];
    int tid = threadIdx.x;
    int lane = tid & 63, wv = tid >> 6;
    int base = 0;
    for (int c0 = 0; c0 < N_TOK; c0 += 1024) {
        int n = c0 + tid;
        unsigned char s = sel[n];
        bool f1 = ((s & 15) == e);
        bool f = f1 || ((s >> 4) == e);
        unsigned long long mask = __ballot(f);
        int prefix = __popcll(mask & ((1ull << lane) - 1ull));
        if (lane == 0) wave_tot[wv] = __popcll(mask);
        __syncthreads();
        if (tid < 16) {
            int wb = 0;
            for (int i = 0; i < tid; ++i) wb += wave_tot[i];
            wave_base[tid] = wb;
        }
        __syncthreads();
        if (f) {
            int pos = base + wave_base[wv] + prefix;
            lists[e * N_TOK + pos] = (n << 1) | (f1 ? 0 : 1);
            float2 w = w2[n];
            wgts[e * N_TOK + pos] = f1 ? w.x : w.y;
        }
        base += wave_base[15] + wave_tot[15];
        __syncthreads();
    }
    if (tid == 0) counts[e] = base;
}

// Fused 2-layer expert FFN over a gathered 32-token tile.
// Flat grid: e = blockIdx&7 (-> XCD e), tile = blockIdx>>3.  512 thr = 8 waves,
// wave w owns output cols [w*64, w*64+64).  LDS: 32x512 bf16 (32KB), swizzled,
// reused X -> H -> y.  SLOT=1: plain coalesced stores into ybuf[(tok<<1)|slot].
// SLOT=0: atomicAdd fallback into out.
template <bool SLOT>
__global__ void __launch_bounds__(512, 4)
k_experts(const float* __restrict__ x,
          const unsigned short* __restrict__ w1f, const float* __restrict__ b1,
          const unsigned short* __restrict__ w2f, const float* __restrict__ b2,
          const int* __restrict__ counts, const int* __restrict__ lists,
          const float* __restrict__ wgts,
          unsigned short* __restrict__ ybuf, float* __restrict__ out) {
    __shared__ unsigned short lds[TILE * D_IN];   // 32 KiB
    __shared__ int   tl[TILE];
    __shared__ float wl[TILE];

    int b = blockIdx.x;
    int e = b & 7;                 // expert -> XCD affinity
    int tile = b >> 3;
    int cnt = counts[e];
    int row0 = tile * TILE;
    if (row0 >= cnt) return;
    int rv = min(TILE, cnt - row0);

    int tid = threadIdx.x;
    int lane = tid & 63;
    int wid = tid >> 6;
    int cw = wid * 64;
    int l15 = lane & 15, l4 = lane >> 4;

    if (tid < TILE) {
        int v = 0; float w = 0.f;
        if (tid < rv) {
            v = lists[e * N_TOK + row0 + tid];
            w = wgts [e * N_TOK + row0 + tid];
        }
        tl[tid] = v; wl[tid] = w;
    }
    __syncthreads();

    // ---- stage gathered X tile (f32 -> bf16, swizzled) ----
    #pragma unroll
    for (int it = 0; it < 8; ++it) {
        int idx = tid + it * 512;
        int r = idx >> 7, c4 = idx & 127;
        float4 v = make_float4(0.f, 0.f, 0.f, 0.f);
        if (r < rv)
            v = ((const float4*)(x + (size_t)(tl[r] >> 1) * D_IN))[c4];
        unsigned lo = (unsigned)f2bf(v.x) | ((unsigned)f2bf(v.y) << 16);
        unsigned hi = (unsigned)f2bf(v.z) | ((unsigned)f2bf(v.w) << 16);
        int off = (r * 1024 + c4 * 8) ^ ((r & 7) << 4);
        *(uint2*)((char*)lds + off) = make_uint2(lo, hi);
    }
    __syncthreads();

    // ---- stage 1: H = gelu(X @ W1^T + b1) ----
    const unsigned short* w1base = w1f + ((size_t)(e * 32 + wid * 4) * 16) * 512 + (size_t)lane * 8;
    f32x4 acc[2][4];
    #pragma unroll
    for (int n = 0; n < 4; ++n) {
        float bv = b1[e * H_DIM + cw + n * 16 + l15];
        #pragma unroll
        for (int m = 0; m < 2; ++m) acc[m][n] = f32x4{bv, bv, bv, bv};
    }
    {
        bf16x8 bb[3][4];
        #pragma unroll
        for (int n = 0; n < 4; ++n) {
            bb[0][n] = *(const bf16x8*)(w1base + (n * 16 + 0) * 512);
            bb[1][n] = *(const bf16x8*)(w1base + (n * 16 + 1) * 512);
        }
        #pragma unroll
        for (int kc = 0; kc < 16; ++kc) {
            if (kc + 2 < 16) {
                #pragma unroll
                for (int n = 0; n < 4; ++n)
                    bb[(kc + 2) % 3][n] = *(const bf16x8*)(w1base + (n * 16 + kc + 2) * 512);
            }
            int k0 = kc * 32 + l4 * 8;
            bf16x8 a[2];
            #pragma unroll
            for (int m = 0; m < 2; ++m) {
                int row = m * 16 + l15;
                int off = (row * 1024 + k0 * 2) ^ ((row & 7) << 4);
                a[m] = *(const bf16x8*)((const char*)lds + off);
            }
            #pragma unroll
            for (int n = 0; n < 4; ++n)
                #pragma unroll
                for (int m = 0; m < 2; ++m)
                    acc[m][n] = __builtin_amdgcn_mfma_f32_16x16x32_bf16(a[m], bb[kc % 3][n], acc[m][n], 0, 0, 0);
        }
    }
    __syncthreads();   // all waves done reading X

    // gelu (exact) + write H back (swizzled)
    #pragma unroll
    for (int m = 0; m < 2; ++m)
        #pragma unroll
        for (int n = 0; n < 4; ++n)
            #pragma unroll
            for (int r = 0; r < 4; ++r) {
                int row = m * 16 + l4 * 4 + r;
                int col = cw + n * 16 + l15;
                float v = acc[m][n][r];
                float g = 0.5f * v * (1.0f + erff(v * 0.70710678118654752f));
                int off = (row * 1024 + col * 2) ^ ((row & 7) << 4);
                *(unsigned short*)((char*)lds + off) = f2bf(g);
            }
    __syncthreads();

    // ---- stage 2: Y = H @ W2^T + b2 ----
    const unsigned short* w2base = w2f + ((size_t)(e * 32 + wid * 4) * 16) * 512 + (size_t)lane * 8;
    #pragma unroll
    for (int n = 0; n < 4; ++n) {
        float bv = b2[e * H_DIM + cw + n * 16 + l15];
        #pragma unroll
        for (int m = 0; m < 2; ++m) acc[m][n] = f32x4{bv, bv, bv, bv};
    }
    {
        bf16x8 bb[3][4];
        #pragma unroll
        for (int n = 0; n < 4; ++n) {
            bb[0][n] = *(const bf16x8*)(w2base + (n * 16 + 0) * 512);
            bb[1][n] = *(const bf16x8*)(w2base + (n * 16 + 1) * 512);
        }
        #pragma unroll
        for (int kc = 0; kc < 16; ++kc) {
            if (kc + 2 < 16) {
                #pragma unroll
                for (int n = 0; n < 4; ++n)
                    bb[(kc + 2) % 3][n] = *(const bf16x8*)(w2base + (n * 16 + kc + 2) * 512);
            }
            int k0 = kc * 32 + l4 * 8;
            bf16x8 a[2];
            #pragma unroll
            for (int m = 0; m < 2; ++m) {
                int row = m * 16 + l15;
                int off = (row * 1024 + k0 * 2) ^ ((row & 7) << 4);
                a[m] = *(const bf16x8*)((const char*)lds + off);
            }
            #pragma unroll
            for (int n = 0; n < 4; ++n)
                #pragma unroll
                for (int m = 0; m < 2; ++m)
                    acc[m][n] = __builtin_amdgcn_mfma_f32_16x16x32_bf16(a[m], bb[kc % 3][n], acc[m][n], 0, 0, 0);
        }
    }

    if (SLOT) {
        __syncthreads();   // all H reads done before overwriting LDS with y
        // y = w * (acc) -> bf16 into LDS (linear layout)
        #pragma unroll
        for (int m = 0; m < 2; ++m)
            #pragma unroll
            for (int n = 0; n < 4; ++n)
                #pragma unroll
                for (int r = 0; r < 4; ++r) {
                    int row = m * 16 + l4 * 4 + r;
                    int col = cw + n * 16 + l15;
                    lds[row * 512 + col] = f2bf(acc[m][n][r] * wl[row]);
                }
        __syncthreads();
        // coalesced write-out: wave w handles rows w*4 .. w*4+3
        #pragma unroll
        for (int rr = 0; rr < 4; ++rr) {
            int row = wid * 4 + rr;
            if (row < rv) {
                int v = tl[row];
                uint4 d = *(uint4*)((char*)lds + row * 1024 + lane * 16);
                *(uint4*)(ybuf + (size_t)v * H_DIM + lane * 8) = d;
            }
        }
    } else {
        #pragma unroll
        for (int m = 0; m < 2; ++m)
            #pragma unroll
            for (int r = 0; r < 4; ++r) {
                int row = m * 16 + l4 * 4 + r;
                if (row < rv) {
                    int t = tl[row] >> 1;
                    float gw = wl[row];
                    #pragma unroll
                    for (int n = 0; n < 4; ++n) {
                        int col = cw + n * 16 + l15;
                        atomicAdd(out + (size_t)t * H_DIM + col, gw * acc[m][n][r]);
                    }
                }
            }
    }
}

// out[n][h] = yb[2n][h] + yb[2n+1][h]   (bf16 -> f32)
__global__ void __launch_bounds__(256) k_combine(const unsigned short* __restrict__ yb,
                                                 float* __restrict__ out) {
    int gid = blockIdx.x * 256 + threadIdx.x;
    int n = gid >> 6;
    int h0 = (gid & 63) * 8;
    const unsigned short* r0 = yb + ((size_t)2 * n) * H_DIM + h0;
    uint4 a = *(const uint4*)r0;
    uint4 b = *(const uint4*)(r0 + H_DIM);
    float o[8];
    unsigned ua[4] = {a.x, a.y, a.z, a.w}, ub[4] = {b.x, b.y, b.z, b.w};
    #pragma unroll
    for (int j = 0; j < 4; ++j) {
        o[2 * j]     = bf2f((unsigned short)(ua[j] & 0xFFFF)) + bf2f((unsigned short)(ub[j] & 0xFFFF));
        o[2 * j + 1] = bf2f((unsigned short)(ua[j] >> 16))    + bf2f((unsigned short)(ub[j] >> 16));
    }
    float* dst = out + (size_t)n * H_DIM + h0;
    *(float4*)dst       = make_float4(o[0], o[1], o[2], o[3]);
    *(float4*)(dst + 4) = make_float4(o[4], o[5], o[6], o[7]);
}

extern "C" void kernel_launch(void* const* d_in, const int* in_sizes, int n_in,
                              void* d_out, int out_size, void* d_ws, size_t ws_size,
                              hipStream_t stream) {
    (void)in_sizes; (void)n_in;
    const float* x  = (const float*)d_in[0];
    const float* Wg = (const float*)d_in[1];
    const float* bg = (const float*)d_in[2];
    const float* W1 = (const float*)d_in[3];
    const float* b1 = (const float*)d_in[4];
    const float* W2 = (const float*)d_in[5];
    const float* b2 = (const float*)d_in[6];
    float* out = (float*)d_out;

    char* ws = (char*)d_ws;
    unsigned short* w1f = (unsigned short*)(ws);                       // 4 MiB
    unsigned short* w2f = (unsigned short*)(ws + (4u << 20));          // 4 MiB
    unsigned short* ybuf= (unsigned short*)(ws + (8u << 20));          // 16 MiB
    char* tail = ws + (24u << 20);
    int*   counts = (int*)(tail);                                      // 32 B
    int*   lists  = (int*)(tail + 256);                                // 256 KiB
    float* wgts   = (float*)(tail + 256 + 262144);                     // 256 KiB
    unsigned char* sel = (unsigned char*)(tail + 256 + 524288);        // 8 KiB
    float2* w2g   = (float2*)(tail + 256 + 532480);                    // 64 KiB
    size_t need = (24u << 20) + 256 + 532480 + 65536;

    bool slot = ws_size >= need;
    if (!slot) {
        // compact fallback layout (atomic epilogue), ~9 MiB
        tail = ws + (8u << 20);
        counts = (int*)(tail);
        lists  = (int*)(tail + 256);
        wgts   = (float*)(tail + 256 + 262144);
        sel    = (unsigned char*)(tail + 256 + 524288);
        w2g    = (float2*)(tail + 256 + 532480);
        hipMemsetAsync(out, 0, (size_t)out_size * sizeof(float), stream);
    }

    k_pack<<<dim3(8, 16, 16), dim3(256), 0, stream>>>(W1, W2, w1f, w2f);
    k_gate<<<dim3(N_TOK / 32), dim3(256), 0, stream>>>(x, Wg, bg, sel, w2g);
    k_build<<<dim3(N_EXP), dim3(1024), 0, stream>>>(sel, w2g, counts, lists, wgts);
    if (slot) {
        k_experts<true><<<dim3(2048), dim3(512), 0, stream>>>(
            x, w1f, b1, w2f, b2, counts, lists, wgts, ybuf, out);
        k_combine<<<dim3(N_TOK * 64 / 256), dim3(256), 0, stream>>>(ybuf, out);
    } else {
        k_experts<false><<<dim3(2048), dim3(512), 0, stream>>>(
            x, w1f, b1, w2f, b2, counts, lists, wgts, ybuf, out);
    }
}

// Round 5
// 191.336 us; speedup vs baseline: 1.5575x; 1.1194x over previous
//
#include <hip/hip_runtime.h>
#include <hip/hip_bf16.h>

// MoE: B=4,T=2048,D=512,E=8,H=512,K=2.  N=8192 tokens.
// v5: gate reads x once (chunked dot + LDS reduce) and emits bf16 x;
// experts gather bf16 (pure copy staging), depth-3 B prefetch.

typedef __bf16 bf16x8 __attribute__((ext_vector_type(8)));
typedef float  f32x4  __attribute__((ext_vector_type(4)));

#define N_TOK 8192
#define D_IN  512
#define N_EXP 8
#define H_DIM 512
#define TILE  32

static __device__ __forceinline__ unsigned short f2bf(float f) {
    union { float f; unsigned u; } v; v.f = f;
    unsigned r = v.u + 0x7FFFu + ((v.u >> 16) & 1u);   // RNE
    return (unsigned short)(r >> 16);
}
static __device__ __forceinline__ float bf2f(unsigned short h) {
    union { unsigned u; float f; } v; v.u = ((unsigned)h) << 16; return v.f;
}

// Pack W1 and W2 (f32 [E][512][512]) into MFMA B-fragment-linear bf16:
// out[((e*32+cb)*16+kc)*512 + lane*8 + j] = bf16(W[e][kc*32+(lane>>4)*8+j][cb*16+(lane&15)])
__global__ void __launch_bounds__(256) k_pack(const float* __restrict__ W1,
                                              const float* __restrict__ W2,
                                              unsigned short* __restrict__ w1f,
                                              unsigned short* __restrict__ w2f) {
    __shared__ float t[32][65];
    int z = blockIdx.z;
    int e = z & 7;
    const float* in = (z < 8) ? W1 : W2;
    unsigned short* out = (z < 8) ? w1f : w2f;
    int cb0 = blockIdx.x * 4;
    int kc  = blockIdx.y;
    const float* src = in + ((size_t)e * 512 + kc * 32) * 512 + blockIdx.x * 64;
    int tid = threadIdx.x;
    int r = tid >> 3, cq = (tid & 7) * 8;
    float4 v0 = *(const float4*)(src + (size_t)r * 512 + cq);
    float4 v1 = *(const float4*)(src + (size_t)r * 512 + cq + 4);
    t[r][cq + 0] = v0.x; t[r][cq + 1] = v0.y; t[r][cq + 2] = v0.z; t[r][cq + 3] = v0.w;
    t[r][cq + 4] = v1.x; t[r][cq + 5] = v1.y; t[r][cq + 6] = v1.z; t[r][cq + 7] = v1.w;
    __syncthreads();
    int g = tid >> 6, lane = tid & 63;
    int l15 = lane & 15, l4 = lane >> 4;
    unsigned v[4];
    #pragma unroll
    for (int j = 0; j < 4; ++j) {
        unsigned lo = f2bf(t[l4 * 8 + 2 * j    ][g * 16 + l15]);
        unsigned hi = f2bf(t[l4 * 8 + 2 * j + 1][g * 16 + l15]);
        v[j] = lo | (hi << 16);
    }
    size_t dst = (((size_t)(e * 32 + cb0 + g) * 16 + kc) * 512) + lane * 8;
    *(uint4*)(out + dst) = make_uint4(v[0], v[1], v[2], v[3]);
}

// Gate v2: block = 256 thr = 32 tokens. Thread (t,c) owns 64-elem chunk c of
// token t's row: x read ONCE, coalesced. Partial dots -> LDS reduce -> top-2.
// Phase 2: convert the block's 32 rows to bf16 (xbf), coalesced.
__global__ void __launch_bounds__(256) k_gate(const float* __restrict__ x,
                                              const float* __restrict__ Wg,
                                              const float* __restrict__ bg,
                                              unsigned char* __restrict__ sel,
                                              float2* __restrict__ w2,
                                              unsigned short* __restrict__ xbf) {
    __shared__ float part[32][8][8];   // [t][c][e]
    __shared__ float lg[32][8];
    int tid = threadIdx.x;
    int t = tid >> 3, c = tid & 7;
    int n0 = blockIdx.x * 32;
    int n = n0 + t;
    const float4* xr = (const float4*)(x + (size_t)n * D_IN + c * 64);
    float acc[8];
    #pragma unroll
    for (int e = 0; e < 8; ++e) acc[e] = 0.f;
    #pragma unroll
    for (int j4 = 0; j4 < 16; ++j4) {
        float4 v = xr[j4];
        int k = c * 64 + j4 * 4;
        float xv[4] = {v.x, v.y, v.z, v.w};
        #pragma unroll
        for (int u = 0; u < 4; ++u) {
            float4 wlo = *(const float4*)(Wg + (size_t)(k + u) * 8);
            float4 whi = *(const float4*)(Wg + (size_t)(k + u) * 8 + 4);
            acc[0] += xv[u] * wlo.x; acc[1] += xv[u] * wlo.y;
            acc[2] += xv[u] * wlo.z; acc[3] += xv[u] * wlo.w;
            acc[4] += xv[u] * whi.x; acc[5] += xv[u] * whi.y;
            acc[6] += xv[u] * whi.z; acc[7] += xv[u] * whi.w;
        }
    }
    #pragma unroll
    for (int e = 0; e < 8; ++e) part[t][c][e] = acc[e];
    __syncthreads();
    {   // thread (t,c) finalizes expert e=c
        float f = bg[c];
        #pragma unroll
        for (int cc = 0; cc < 8; ++cc) f += part[t][cc][c];
        lg[t][c] = f;
    }
    __syncthreads();
    if (c == 0) {
        float best = lg[t][0]; int i1 = 0;
        #pragma unroll
        for (int j = 1; j < 8; ++j) { float v = lg[t][j]; if (v > best) { best = v; i1 = j; } }
        float best2 = -1e30f; int i2 = 0;
        #pragma unroll
        for (int j = 0; j < 8; ++j) {
            if (j == i1) continue;
            float v = lg[t][j]; if (v > best2) { best2 = v; i2 = j; }
        }
        float tt = expf(best2 - best);
        float w0 = 1.0f / (1.0f + tt);
        sel[n] = (unsigned char)(i1 | (i2 << 4));
        w2[n] = make_float2(w0, 1.0f - w0);
    }
    // phase 2: f32 -> bf16 copy of this block's 32 rows (reads hit L1/L2)
    #pragma unroll
    for (int i = 0; i < 8; ++i) {
        int idx = tid + i * 256;          // 2048 groups of 8 elems
        int r = idx >> 6, g = idx & 63;
        const float* src = x + (size_t)(n0 + r) * D_IN + g * 8;
        float4 a = *(const float4*)src;
        float4 b = *(const float4*)(src + 4);
        unsigned u0 = (unsigned)f2bf(a.x) | ((unsigned)f2bf(a.y) << 16);
        unsigned u1 = (unsigned)f2bf(a.z) | ((unsigned)f2bf(a.w) << 16);
        unsigned u2 = (unsigned)f2bf(b.x) | ((unsigned)f2bf(b.y) << 16);
        unsigned u3 = (unsigned)f2bf(b.z) | ((unsigned)f2bf(b.w) << 16);
        *(uint4*)(xbf + (size_t)(n0 + r) * D_IN + g * 8) = make_uint4(u0, u1, u2, u3);
    }
}

// Build per-expert compacted token lists; deterministic ballot/prefix scan.
// lists entry = (token<<1) | slot  (slot 0 = top1, 1 = top2).
__global__ void __launch_bounds__(1024) k_build(const unsigned char* __restrict__ sel,
                                                const float2* __restrict__ w2,
                                                int* __restrict__ counts,
                                                int* __restrict__ lists,
                                                float* __restrict__ wgts) {
    int e = blockIdx.x;
    __shared__ int wave_tot[16], wave_base[16];
    int tid = threadIdx.x;
    int lane = tid & 63, wv = tid >> 6;
    int base = 0;
    for (int c0 = 0; c0 < N_TOK; c0 += 1024) {
        int n = c0 + tid;
        unsigned char s = sel[n];
        bool f1 = ((s & 15) == e);
        bool f = f1 || ((s >> 4) == e);
        unsigned long long mask = __ballot(f);
        int prefix = __popcll(mask & ((1ull << lane) - 1ull));
        if (lane == 0) wave_tot[wv] = __popcll(mask);
        __syncthreads();
        if (tid < 16) {
            int wb = 0;
            for (int i = 0; i < tid; ++i) wb += wave_tot[i];
            wave_base[tid] = wb;
        }
        __syncthreads();
        if (f) {
            int pos = base + wave_base[wv] + prefix;
            lists[e * N_TOK + pos] = (n << 1) | (f1 ? 0 : 1);
            float2 w = w2[n];
            wgts[e * N_TOK + pos] = f1 ? w.x : w.y;
        }
        base += wave_base[15] + wave_tot[15];
        __syncthreads();
    }
    if (tid == 0) counts[e] = base;
}

// Fused 2-layer expert FFN over a gathered 32-token tile (bf16 gather).
// Flat grid: e = blockIdx&7 (-> XCD e), tile = blockIdx>>3.  512 thr = 8 waves,
// wave w owns output cols [w*64, w*64+64).  LDS: 32x512 bf16, swizzled,
// reused X -> H -> y.  Depth-3 ring-4 B prefetch.
template <bool SLOT>
__global__ void __launch_bounds__(512, 4)
k_experts(const unsigned short* __restrict__ xbf,
          const unsigned short* __restrict__ w1f, const float* __restrict__ b1,
          const unsigned short* __restrict__ w2f, const float* __restrict__ b2,
          const int* __restrict__ counts, const int* __restrict__ lists,
          const float* __restrict__ wgts,
          unsigned short* __restrict__ ybuf, float* __restrict__ out) {
    __shared__ unsigned short lds[TILE * D_IN];   // 32 KiB
    __shared__ int   tl[TILE];
    __shared__ float wl[TILE];

    int b = blockIdx.x;
    int e = b & 7;
    int tile = b >> 3;
    int cnt = counts[e];
    int row0 = tile * TILE;
    if (row0 >= cnt) return;
    int rv = min(TILE, cnt - row0);

    int tid = threadIdx.x;
    int lane = tid & 63;
    int wid = tid >> 6;
    int cw = wid * 64;
    int l15 = lane & 15, l4 = lane >> 4;

    if (tid < TILE) {
        int v = 0; float w = 0.f;
        if (tid < rv) {
            v = lists[e * N_TOK + row0 + tid];
            w = wgts [e * N_TOK + row0 + tid];
        }
        tl[tid] = v; wl[tid] = w;
    }
    __syncthreads();

    // ---- stage gathered bf16 X tile (pure uint4 copy, swizzled) ----
    #pragma unroll
    for (int it = 0; it < 4; ++it) {
        int idx = tid + it * 512;         // 2048 groups of 8 bf16 (16B)
        int r = idx >> 6, g = idx & 63;
        uint4 v = make_uint4(0, 0, 0, 0);
        if (r < rv)
            v = *(const uint4*)(xbf + (size_t)(tl[r] >> 1) * D_IN + g * 8);
        int off = (r * 1024 + g * 16) ^ ((r & 7) << 4);
        *(uint4*)((char*)lds + off) = v;
    }
    __syncthreads();

    // ---- stage 1: H = gelu(X @ W1^T + b1) ----
    const unsigned short* w1base = w1f + ((size_t)(e * 32 + wid * 4) * 16) * 512 + (size_t)lane * 8;
    f32x4 acc[2][4];
    #pragma unroll
    for (int n = 0; n < 4; ++n) {
        float bv = b1[e * H_DIM + cw + n * 16 + l15];
        #pragma unroll
        for (int m = 0; m < 2; ++m) acc[m][n] = f32x4{bv, bv, bv, bv};
    }
    {
        bf16x8 bb[4][4];
        #pragma unroll
        for (int n = 0; n < 4; ++n) {
            bb[0][n] = *(const bf16x8*)(w1base + (n * 16 + 0) * 512);
            bb[1][n] = *(const bf16x8*)(w1base + (n * 16 + 1) * 512);
            bb[2][n] = *(const bf16x8*)(w1base + (n * 16 + 2) * 512);
        }
        #pragma unroll
        for (int kc = 0; kc < 16; ++kc) {
            if (kc + 3 < 16) {
                #pragma unroll
                for (int n = 0; n < 4; ++n)
                    bb[(kc + 3) & 3][n] = *(const bf16x8*)(w1base + (n * 16 + kc + 3) * 512);
            }
            int k0 = kc * 32 + l4 * 8;
            bf16x8 a[2];
            #pragma unroll
            for (int m = 0; m < 2; ++m) {
                int row = m * 16 + l15;
                int off = (row * 1024 + k0 * 2) ^ ((row & 7) << 4);
                a[m] = *(const bf16x8*)((const char*)lds + off);
            }
            #pragma unroll
            for (int n = 0; n < 4; ++n)
                #pragma unroll
                for (int m = 0; m < 2; ++m)
                    acc[m][n] = __builtin_amdgcn_mfma_f32_16x16x32_bf16(a[m], bb[kc & 3][n], acc[m][n], 0, 0, 0);
        }
    }
    __syncthreads();

    // gelu (exact) + write H back (swizzled)
    #pragma unroll
    for (int m = 0; m < 2; ++m)
        #pragma unroll
        for (int n = 0; n < 4; ++n)
            #pragma unroll
            for (int r = 0; r < 4; ++r) {
                int row = m * 16 + l4 * 4 + r;
                int col = cw + n * 16 + l15;
                float v = acc[m][n][r];
                float g = 0.5f * v * (1.0f + erff(v * 0.70710678118654752f));
                int off = (row * 1024 + col * 2) ^ ((row & 7) << 4);
                *(unsigned short*)((char*)lds + off) = f2bf(g);
            }
    __syncthreads();

    // ---- stage 2: Y = H @ W2^T + b2 ----
    const unsigned short* w2base = w2f + ((size_t)(e * 32 + wid * 4) * 16) * 512 + (size_t)lane * 8;
    #pragma unroll
    for (int n = 0; n < 4; ++n) {
        float bv = b2[e * H_DIM + cw + n * 16 + l15];
        #pragma unroll
        for (int m = 0; m < 2; ++m) acc[m][n] = f32x4{bv, bv, bv, bv};
    }
    {
        bf16x8 bb[4][4];
        #pragma unroll
        for (int n = 0; n < 4; ++n) {
            bb[0][n] = *(const bf16x8*)(w2base + (n * 16 + 0) * 512);
            bb[1][n] = *(const bf16x8*)(w2base + (n * 16 + 1) * 512);
            bb[2][n] = *(const bf16x8*)(w2base + (n * 16 + 2) * 512);
        }
        #pragma unroll
        for (int kc = 0; kc < 16; ++kc) {
            if (kc + 3 < 16) {
                #pragma unroll
                for (int n = 0; n < 4; ++n)
                    bb[(kc + 3) & 3][n] = *(const bf16x8*)(w2base + (n * 16 + kc + 3) * 512);
            }
            int k0 = kc * 32 + l4 * 8;
            bf16x8 a[2];
            #pragma unroll
            for (int m = 0; m < 2; ++m) {
                int row = m * 16 + l15;
                int off = (row * 1024 + k0 * 2) ^ ((row & 7) << 4);
                a[m] = *(const bf16x8*)((const char*)lds + off);
            }
            #pragma unroll
            for (int n = 0; n < 4; ++n)
                #pragma unroll
                for (int m = 0; m < 2; ++m)
                    acc[m][n] = __builtin_amdgcn_mfma_f32_16x16x32_bf16(a[m], bb[kc & 3][n], acc[m][n], 0, 0, 0);
        }
    }

    if (SLOT) {
        __syncthreads();
        #pragma unroll
        for (int m = 0; m < 2; ++m)
            #pragma unroll
            for (int n = 0; n < 4; ++n)
                #pragma unroll
                for (int r = 0; r < 4; ++r) {
                    int row = m * 16 + l4 * 4 + r;
                    int col = cw + n * 16 + l15;
                    lds[row * 512 + col] = f2bf(acc[m][n][r] * wl[row]);
                }
        __syncthreads();
        #pragma unroll
        for (int rr = 0; rr < 4; ++rr) {
            int row = wid * 4 + rr;
            if (row < rv) {
                int v = tl[row];
                uint4 d = *(uint4*)((char*)lds + row * 1024 + lane * 16);
                *(uint4*)(ybuf + (size_t)v * H_DIM + lane * 8) = d;
            }
        }
    } else {
        #pragma unroll
        for (int m = 0; m < 2; ++m)
            #pragma unroll
            for (int r = 0; r < 4; ++r) {
                int row = m * 16 + l4 * 4 + r;
                if (row < rv) {
                    int t = tl[row] >> 1;
                    float gw = wl[row];
                    #pragma unroll
                    for (int n = 0; n < 4; ++n) {
                        int col = cw + n * 16 + l15;
                        atomicAdd(out + (size_t)t * H_DIM + col, gw * acc[m][n][r]);
                    }
                }
            }
    }
}

// out[n][h] = yb[2n][h] + yb[2n+1][h]   (bf16 -> f32)
__global__ void __launch_bounds__(256) k_combine(const unsigned short* __restrict__ yb,
                                                 float* __restrict__ out) {
    int gid = blockIdx.x * 256 + threadIdx.x;
    int n = gid >> 6;
    int h0 = (gid & 63) * 8;
    const unsigned short* r0 = yb + ((size_t)2 * n) * H_DIM + h0;
    uint4 a = *(const uint4*)r0;
    uint4 b = *(const uint4*)(r0 + H_DIM);
    float o[8];
    unsigned ua[4] = {a.x, a.y, a.z, a.w}, ub[4] = {b.x, b.y, b.z, b.w};
    #pragma unroll
    for (int j = 0; j < 4; ++j) {
        o[2 * j]     = bf2f((unsigned short)(ua[j] & 0xFFFF)) + bf2f((unsigned short)(ub[j] & 0xFFFF));
        o[2 * j + 1] = bf2f((unsigned short)(ua[j] >> 16))    + bf2f((unsigned short)(ub[j] >> 16));
    }
    float* dst = out + (size_t)n * H_DIM + h0;
    *(float4*)dst       = make_float4(o[0], o[1], o[2], o[3]);
    *(float4*)(dst + 4) = make_float4(o[4], o[5], o[6], o[7]);
}

extern "C" void kernel_launch(void* const* d_in, const int* in_sizes, int n_in,
                              void* d_out, int out_size, void* d_ws, size_t ws_size,
                              hipStream_t stream) {
    (void)in_sizes; (void)n_in;
    const float* x  = (const float*)d_in[0];
    const float* Wg = (const float*)d_in[1];
    const float* bg = (const float*)d_in[2];
    const float* W1 = (const float*)d_in[3];
    const float* b1 = (const float*)d_in[4];
    const float* W2 = (const float*)d_in[5];
    const float* b2 = (const float*)d_in[6];
    float* out = (float*)d_out;

    char* ws = (char*)d_ws;
    unsigned short* w1f = (unsigned short*)(ws);                       // 4 MiB
    unsigned short* w2f = (unsigned short*)(ws + (4u << 20));          // 4 MiB
    unsigned short* ybuf= (unsigned short*)(ws + (8u << 20));          // 16 MiB
    unsigned short* xbf = (unsigned short*)(ws + (24u << 20));         // 8 MiB
    char* tail = ws + (32u << 20);
    int*   counts = (int*)(tail);                                      // 32 B
    int*   lists  = (int*)(tail + 256);                                // 256 KiB
    float* wgts   = (float*)(tail + 256 + 262144);                     // 256 KiB
    unsigned char* sel = (unsigned char*)(tail + 256 + 524288);        // 8 KiB
    float2* w2g   = (float2*)(tail + 256 + 532480);                    // 64 KiB
    size_t need = (32u << 20) + 256 + 532480 + 65536;

    bool slot = ws_size >= need;
    if (!slot) {
        // compact fallback (atomic epilogue): w1f, w2f, xbf, tail
        xbf  = (unsigned short*)(ws + (8u << 20));
        tail = ws + (16u << 20);
        counts = (int*)(tail);
        lists  = (int*)(tail + 256);
        wgts   = (float*)(tail + 256 + 262144);
        sel    = (unsigned char*)(tail + 256 + 524288);
        w2g    = (float2*)(tail + 256 + 532480);
        hipMemsetAsync(out, 0, (size_t)out_size * sizeof(float), stream);
    }

    k_pack<<<dim3(8, 16, 16), dim3(256), 0, stream>>>(W1, W2, w1f, w2f);
    k_gate<<<dim3(N_TOK / 32), dim3(256), 0, stream>>>(x, Wg, bg, sel, w2g, xbf);
    k_build<<<dim3(N_EXP), dim3(1024), 0, stream>>>(sel, w2g, counts, lists, wgts);
    if (slot) {
        k_experts<true><<<dim3(2048), dim3(512), 0, stream>>>(
            xbf, w1f, b1, w2f, b2, counts, lists, wgts, ybuf, out);
        k_combine<<<dim3(N_TOK * 64 / 256), dim3(256), 0, stream>>>(ybuf, out);
    } else {
        k_experts<false><<<dim3(2048), dim3(512), 0, stream>>>(
            xbf, w1f, b1, w2f, b2, counts, lists, wgts, ybuf, out);
    }
}

// Round 6
// 188.145 us; speedup vs baseline: 1.5839x; 1.0170x over previous
//
#include <hip/hip_runtime.h>
#include <hip/hip_bf16.h>

// MoE: B=4,T=2048,D=512,E=8,H=512,K=2.  N=8192 tokens.
// v6: 64-token blocks = two 32-row A-tiles register-blocked against each
// B-fragment load (halves per-XCD L2 weight traffic, doubles MFMA ILP).
// No xbf (proved neutral). Slot-store epilogue + combine (no atomics).

typedef __bf16 bf16x8 __attribute__((ext_vector_type(8)));
typedef float  f32x4  __attribute__((ext_vector_type(4)));

#define N_TOK 8192
#define D_IN  512
#define N_EXP 8
#define H_DIM 512
#define TILE  64          // tokens per block (2 x 32-row sub-tiles)

static __device__ __forceinline__ unsigned short f2bf(float f) {
    union { float f; unsigned u; } v; v.f = f;
    unsigned r = v.u + 0x7FFFu + ((v.u >> 16) & 1u);   // RNE
    return (unsigned short)(r >> 16);
}
static __device__ __forceinline__ float bf2f(unsigned short h) {
    union { unsigned u; float f; } v; v.u = ((unsigned)h) << 16; return v.f;
}

// Pack W1 and W2 (f32 [E][512][512]) into MFMA B-fragment-linear bf16:
// out[((e*32+cb)*16+kc)*512 + lane*8 + j] = bf16(W[e][kc*32+(lane>>4)*8+j][cb*16+(lane&15)])
__global__ void __launch_bounds__(256) k_pack(const float* __restrict__ W1,
                                              const float* __restrict__ W2,
                                              unsigned short* __restrict__ w1f,
                                              unsigned short* __restrict__ w2f) {
    __shared__ float t[32][65];
    int z = blockIdx.z;
    int e = z & 7;
    const float* in = (z < 8) ? W1 : W2;
    unsigned short* out = (z < 8) ? w1f : w2f;
    int cb0 = blockIdx.x * 4;
    int kc  = blockIdx.y;
    const float* src = in + ((size_t)e * 512 + kc * 32) * 512 + blockIdx.x * 64;
    int tid = threadIdx.x;
    int r = tid >> 3, cq = (tid & 7) * 8;
    float4 v0 = *(const float4*)(src + (size_t)r * 512 + cq);
    float4 v1 = *(const float4*)(src + (size_t)r * 512 + cq + 4);
    t[r][cq + 0] = v0.x; t[r][cq + 1] = v0.y; t[r][cq + 2] = v0.z; t[r][cq + 3] = v0.w;
    t[r][cq + 4] = v1.x; t[r][cq + 5] = v1.y; t[r][cq + 6] = v1.z; t[r][cq + 7] = v1.w;
    __syncthreads();
    int g = tid >> 6, lane = tid & 63;
    int l15 = lane & 15, l4 = lane >> 4;
    unsigned v[4];
    #pragma unroll
    for (int j = 0; j < 4; ++j) {
        unsigned lo = f2bf(t[l4 * 8 + 2 * j    ][g * 16 + l15]);
        unsigned hi = f2bf(t[l4 * 8 + 2 * j + 1][g * 16 + l15]);
        v[j] = lo | (hi << 16);
    }
    size_t dst = (((size_t)(e * 32 + cb0 + g) * 16 + kc) * 512) + lane * 8;
    *(uint4*)(out + dst) = make_uint4(v[0], v[1], v[2], v[3]);
}

// Gate: block = 256 thr = 32 tokens. Thread (t,c) owns 64-elem chunk c of
// token t's row: x read ONCE, coalesced. Partial dots -> LDS reduce -> top-2.
__global__ void __launch_bounds__(256) k_gate(const float* __restrict__ x,
                                              const float* __restrict__ Wg,
                                              const float* __restrict__ bg,
                                              unsigned char* __restrict__ sel,
                                              float2* __restrict__ w2) {
    __shared__ float part[32][8][8];   // [t][c][e]
    __shared__ float lg[32][8];
    int tid = threadIdx.x;
    int t = tid >> 3, c = tid & 7;
    int n = blockIdx.x * 32 + t;
    const float4* xr = (const float4*)(x + (size_t)n * D_IN + c * 64);
    float acc[8];
    #pragma unroll
    for (int e = 0; e < 8; ++e) acc[e] = 0.f;
    #pragma unroll
    for (int j4 = 0; j4 < 16; ++j4) {
        float4 v = xr[j4];
        int k = c * 64 + j4 * 4;
        float xv[4] = {v.x, v.y, v.z, v.w};
        #pragma unroll
        for (int u = 0; u < 4; ++u) {
            float4 wlo = *(const float4*)(Wg + (size_t)(k + u) * 8);
            float4 whi = *(const float4*)(Wg + (size_t)(k + u) * 8 + 4);
            acc[0] += xv[u] * wlo.x; acc[1] += xv[u] * wlo.y;
            acc[2] += xv[u] * wlo.z; acc[3] += xv[u] * wlo.w;
            acc[4] += xv[u] * whi.x; acc[5] += xv[u] * whi.y;
            acc[6] += xv[u] * whi.z; acc[7] += xv[u] * whi.w;
        }
    }
    #pragma unroll
    for (int e = 0; e < 8; ++e) part[t][c][e] = acc[e];
    __syncthreads();
    {
        float f = bg[c];
        #pragma unroll
        for (int cc = 0; cc < 8; ++cc) f += part[t][cc][c];
        lg[t][c] = f;
    }
    __syncthreads();
    if (c == 0) {
        float best = lg[t][0]; int i1 = 0;
        #pragma unroll
        for (int j = 1; j < 8; ++j) { float v = lg[t][j]; if (v > best) { best = v; i1 = j; } }
        float best2 = -1e30f; int i2 = 0;
        #pragma unroll
        for (int j = 0; j < 8; ++j) {
            if (j == i1) continue;
            float v = lg[t][j]; if (v > best2) { best2 = v; i2 = j; }
        }
        float tt = expf(best2 - best);
        float w0 = 1.0f / (1.0f + tt);
        sel[n] = (unsigned char)(i1 | (i2 << 4));
        w2[n] = make_float2(w0, 1.0f - w0);
    }
}

// Build per-expert compacted token lists; deterministic ballot/prefix scan.
// lists entry = (token<<1) | slot  (slot 0 = top1, 1 = top2).
__global__ void __launch_bounds__(1024) k_build(const unsigned char* __restrict__ sel,
                                                const float2* __restrict__ w2,
                                                int* __restrict__ counts,
                                                int* __restrict__ lists,
                                                float* __restrict__ wgts) {
    int e = blockIdx.x;
    __shared__ int wave_tot[16], wave_base[16];
    int tid = threadIdx.x;
    int lane = tid & 63, wv = tid >> 6;
    int base = 0;
    for (int c0 = 0; c0 < N_TOK; c0 += 1024) {
        int n = c0 + tid;
        unsigned char s = sel[n];
        bool f1 = ((s & 15) == e);
        bool f = f1 || ((s >> 4) == e);
        unsigned long long mask = __ballot(f);
        int prefix = __popcll(mask & ((1ull << lane) - 1ull));
        if (lane == 0) wave_tot[wv] = __popcll(mask);
        __syncthreads();
        if (tid < 16) {
            int wb = 0;
            for (int i = 0; i < tid; ++i) wb += wave_tot[i];
            wave_base[tid] = wb;
        }
        __syncthreads();
        if (f) {
            int pos = base + wave_base[wv] + prefix;
            lists[e * N_TOK + pos] = (n << 1) | (f1 ? 0 : 1);
            float2 w = w2[n];
            wgts[e * N_TOK + pos] = f1 ? w.x : w.y;
        }
        base += wave_base[15] + wave_tot[15];
        __syncthreads();
    }
    if (tid == 0) counts[e] = base;
}

// Fused 2-layer expert FFN over a gathered 64-token tile (two 32-row
// sub-tiles A and B register-blocked against shared B-fragments).
// Flat grid: e = blk&7 (-> XCD e), tile = blk>>3.  512 thr = 8 waves,
// wave w owns output cols [w*64, w*64+64).
// LDS: two 32x512 bf16 swizzled buffers (64 KB), reused X -> H -> y.
template <bool SLOT>
__global__ void __launch_bounds__(512, 2)
k_experts(const float* __restrict__ x,
          const unsigned short* __restrict__ w1f, const float* __restrict__ b1,
          const unsigned short* __restrict__ w2f, const float* __restrict__ b2,
          const int* __restrict__ counts, const int* __restrict__ lists,
          const float* __restrict__ wgts,
          unsigned short* __restrict__ ybuf, float* __restrict__ out) {
    __shared__ unsigned short ldsA[32 * D_IN];   // 32 KiB
    __shared__ unsigned short ldsB[32 * D_IN];   // 32 KiB
    __shared__ int   tl[TILE];
    __shared__ float wl[TILE];

    int b = blockIdx.x;
    int e = b & 7;
    int tile = b >> 3;
    int cnt = counts[e];
    int row0 = tile * TILE;
    if (row0 >= cnt) return;
    int rv = min(TILE, cnt - row0);

    int tid = threadIdx.x;
    int lane = tid & 63;
    int wid = tid >> 6;
    int cw = wid * 64;
    int l15 = lane & 15, l4 = lane >> 4;

    if (tid < TILE) {
        int v = 0; float w = 0.f;
        if (tid < rv) {
            v = lists[e * N_TOK + row0 + tid];
            w = wgts [e * N_TOK + row0 + tid];
        }
        tl[tid] = v; wl[tid] = w;
    }
    __syncthreads();

    // ---- stage gathered X (f32 -> bf16, swizzled) into ldsA (rows 0-31)
    //      and ldsB (rows 32-63) ----
    #pragma unroll
    for (int it = 0; it < 16; ++it) {
        int idx = tid + it * 512;            // 8192 float4-groups
        int r = idx >> 7, c4 = idx & 127;    // r: 0..63
        float4 v = make_float4(0.f, 0.f, 0.f, 0.f);
        if (r < rv)
            v = ((const float4*)(x + (size_t)(tl[r] >> 1) * D_IN))[c4];
        unsigned lo = (unsigned)f2bf(v.x) | ((unsigned)f2bf(v.y) << 16);
        unsigned hi = (unsigned)f2bf(v.z) | ((unsigned)f2bf(v.w) << 16);
        int rr = r & 31;
        int off = (rr * 1024 + c4 * 8) ^ ((rr & 7) << 4);
        char* base = (r < 32) ? (char*)ldsA : (char*)ldsB;
        *(uint2*)(base + off) = make_uint2(lo, hi);
    }
    __syncthreads();

    f32x4 accA[2][4], accB[2][4];

    // ================= layer 1: H = gelu(X @ W1^T + b1) =================
    {
        const unsigned short* wbase = w1f + ((size_t)(e * 32 + wid * 4) * 16) * 512 + (size_t)lane * 8;
        #pragma unroll
        for (int n = 0; n < 4; ++n) {
            float bv = b1[e * H_DIM + cw + n * 16 + l15];
            #pragma unroll
            for (int m = 0; m < 2; ++m) { accA[m][n] = f32x4{bv, bv, bv, bv}; accB[m][n] = f32x4{bv, bv, bv, bv}; }
        }
        bf16x8 bb[4][4];
        #pragma unroll
        for (int n = 0; n < 4; ++n) {
            bb[0][n] = *(const bf16x8*)(wbase + (n * 16 + 0) * 512);
            bb[1][n] = *(const bf16x8*)(wbase + (n * 16 + 1) * 512);
            bb[2][n] = *(const bf16x8*)(wbase + (n * 16 + 2) * 512);
        }
        #pragma unroll
        for (int kc = 0; kc < 16; ++kc) {
            if (kc + 3 < 16) {
                #pragma unroll
                for (int n = 0; n < 4; ++n)
                    bb[(kc + 3) & 3][n] = *(const bf16x8*)(wbase + (n * 16 + kc + 3) * 512);
            }
            int k0 = kc * 32 + l4 * 8;
            bf16x8 aA[2], aB[2];
            #pragma unroll
            for (int m = 0; m < 2; ++m) {
                int row = m * 16 + l15;
                int off = (row * 1024 + k0 * 2) ^ ((row & 7) << 4);
                aA[m] = *(const bf16x8*)((const char*)ldsA + off);
                aB[m] = *(const bf16x8*)((const char*)ldsB + off);
            }
            #pragma unroll
            for (int n = 0; n < 4; ++n) {
                #pragma unroll
                for (int m = 0; m < 2; ++m) {
                    accA[m][n] = __builtin_amdgcn_mfma_f32_16x16x32_bf16(aA[m], bb[kc & 3][n], accA[m][n], 0, 0, 0);
                    accB[m][n] = __builtin_amdgcn_mfma_f32_16x16x32_bf16(aB[m], bb[kc & 3][n], accB[m][n], 0, 0, 0);
                }
            }
        }
    }
    __syncthreads();

    // gelu (exact) + write H back (swizzled), A and B buffers
    #pragma unroll
    for (int m = 0; m < 2; ++m)
        #pragma unroll
        for (int n = 0; n < 4; ++n)
            #pragma unroll
            for (int r = 0; r < 4; ++r) {
                int row = m * 16 + l4 * 4 + r;
                int col = cw + n * 16 + l15;
                int off = (row * 1024 + col * 2) ^ ((row & 7) << 4);
                float vA = accA[m][n][r];
                float gA = 0.5f * vA * (1.0f + erff(vA * 0.70710678118654752f));
                *(unsigned short*)((char*)ldsA + off) = f2bf(gA);
                float vB = accB[m][n][r];
                float gB = 0.5f * vB * (1.0f + erff(vB * 0.70710678118654752f));
                *(unsigned short*)((char*)ldsB + off) = f2bf(gB);
            }
    __syncthreads();

    // ================= layer 2: Y = H @ W2^T + b2 =================
    {
        const unsigned short* wbase = w2f + ((size_t)(e * 32 + wid * 4) * 16) * 512 + (size_t)lane * 8;
        #pragma unroll
        for (int n = 0; n < 4; ++n) {
            float bv = b2[e * H_DIM + cw + n * 16 + l15];
            #pragma unroll
            for (int m = 0; m < 2; ++m) { accA[m][n] = f32x4{bv, bv, bv, bv}; accB[m][n] = f32x4{bv, bv, bv, bv}; }
        }
        bf16x8 bb[4][4];
        #pragma unroll
        for (int n = 0; n < 4; ++n) {
            bb[0][n] = *(const bf16x8*)(wbase + (n * 16 + 0) * 512);
            bb[1][n] = *(const bf16x8*)(wbase + (n * 16 + 1) * 512);
            bb[2][n] = *(const bf16x8*)(wbase + (n * 16 + 2) * 512);
        }
        #pragma unroll
        for (int kc = 0; kc < 16; ++kc) {
            if (kc + 3 < 16) {
                #pragma unroll
                for (int n = 0; n < 4; ++n)
                    bb[(kc + 3) & 3][n] = *(const bf16x8*)(wbase + (n * 16 + kc + 3) * 512);
            }
            int k0 = kc * 32 + l4 * 8;
            bf16x8 aA[2], aB[2];
            #pragma unroll
            for (int m = 0; m < 2; ++m) {
                int row = m * 16 + l15;
                int off = (row * 1024 + k0 * 2) ^ ((row & 7) << 4);
                aA[m] = *(const bf16x8*)((const char*)ldsA + off);
                aB[m] = *(const bf16x8*)((const char*)ldsB + off);
            }
            #pragma unroll
            for (int n = 0; n < 4; ++n) {
                #pragma unroll
                for (int m = 0; m < 2; ++m) {
                    accA[m][n] = __builtin_amdgcn_mfma_f32_16x16x32_bf16(aA[m], bb[kc & 3][n], accA[m][n], 0, 0, 0);
                    accB[m][n] = __builtin_amdgcn_mfma_f32_16x16x32_bf16(aB[m], bb[kc & 3][n], accB[m][n], 0, 0, 0);
                }
            }
        }
    }

    if (SLOT) {
        __syncthreads();
        // y = w * acc -> bf16 into LDS (linear layout)
        #pragma unroll
        for (int m = 0; m < 2; ++m)
            #pragma unroll
            for (int n = 0; n < 4; ++n)
                #pragma unroll
                for (int r = 0; r < 4; ++r) {
                    int row = m * 16 + l4 * 4 + r;
                    int col = cw + n * 16 + l15;
                    ldsA[row * 512 + col] = f2bf(accA[m][n][r] * wl[row]);
                    ldsB[row * 512 + col] = f2bf(accB[m][n][r] * wl[row + 32]);
                }
        __syncthreads();
        // coalesced write-out: wave w handles rows w*8 .. w*8+7 (of 64)
        #pragma unroll
        for (int rr = 0; rr < 8; ++rr) {
            int row = wid * 8 + rr;
            if (row < rv) {
                int v = tl[row];
                const unsigned short* src = (row < 32) ? ldsA : ldsB;
                uint4 d = *(uint4*)((char*)src + (row & 31) * 1024 + lane * 16);
                *(uint4*)(ybuf + (size_t)v * H_DIM + lane * 8) = d;
            }
        }
    } else {
        #pragma unroll
        for (int m = 0; m < 2; ++m)
            #pragma unroll
            for (int r = 0; r < 4; ++r) {
                int rowA = m * 16 + l4 * 4 + r;
                int rowB = rowA + 32;
                #pragma unroll
                for (int n = 0; n < 4; ++n) {
                    int col = cw + n * 16 + l15;
                    if (rowA < rv)
                        atomicAdd(out + (size_t)(tl[rowA] >> 1) * H_DIM + col, wl[rowA] * accA[m][n][r]);
                    if (rowB < rv)
                        atomicAdd(out + (size_t)(tl[rowB] >> 1) * H_DIM + col, wl[rowB] * accB[m][n][r]);
                }
            }
    }
}

// out[n][h] = yb[2n][h] + yb[2n+1][h]   (bf16 -> f32)
__global__ void __launch_bounds__(256) k_combine(const unsigned short* __restrict__ yb,
                                                 float* __restrict__ out) {
    int gid = blockIdx.x * 256 + threadIdx.x;
    int n = gid >> 6;
    int h0 = (gid & 63) * 8;
    const unsigned short* r0 = yb + ((size_t)2 * n) * H_DIM + h0;
    uint4 a = *(const uint4*)r0;
    uint4 b = *(const uint4*)(r0 + H_DIM);
    float o[8];
    unsigned ua[4] = {a.x, a.y, a.z, a.w}, ub[4] = {b.x, b.y, b.z, b.w};
    #pragma unroll
    for (int j = 0; j < 4; ++j) {
        o[2 * j]     = bf2f((unsigned short)(ua[j] & 0xFFFF)) + bf2f((unsigned short)(ub[j] & 0xFFFF));
        o[2 * j + 1] = bf2f((unsigned short)(ua[j] >> 16))    + bf2f((unsigned short)(ub[j] >> 16));
    }
    float* dst = out + (size_t)n * H_DIM + h0;
    *(float4*)dst       = make_float4(o[0], o[1], o[2], o[3]);
    *(float4*)(dst + 4) = make_float4(o[4], o[5], o[6], o[7]);
}

extern "C" void kernel_launch(void* const* d_in, const int* in_sizes, int n_in,
                              void* d_out, int out_size, void* d_ws, size_t ws_size,
                              hipStream_t stream) {
    (void)in_sizes; (void)n_in;
    const float* x  = (const float*)d_in[0];
    const float* Wg = (const float*)d_in[1];
    const float* bg = (const float*)d_in[2];
    const float* W1 = (const float*)d_in[3];
    const float* b1 = (const float*)d_in[4];
    const float* W2 = (const float*)d_in[5];
    const float* b2 = (const float*)d_in[6];
    float* out = (float*)d_out;

    char* ws = (char*)d_ws;
    unsigned short* w1f = (unsigned short*)(ws);                       // 4 MiB
    unsigned short* w2f = (unsigned short*)(ws + (4u << 20));          // 4 MiB
    unsigned short* ybuf= (unsigned short*)(ws + (8u << 20));          // 16 MiB
    char* tail = ws + (24u << 20);
    int*   counts = (int*)(tail);                                      // 32 B
    int*   lists  = (int*)(tail + 256);                                // 256 KiB
    float* wgts   = (float*)(tail + 256 + 262144);                     // 256 KiB
    unsigned char* sel = (unsigned char*)(tail + 256 + 524288);        // 8 KiB
    float2* w2g   = (float2*)(tail + 256 + 532480);                    // 64 KiB
    size_t need = (24u << 20) + 256 + 532480 + 65536;

    bool slot = ws_size >= need;
    if (!slot) {
        // compact fallback (atomic epilogue): w1f, w2f, tail
        tail = ws + (8u << 20);
        counts = (int*)(tail);
        lists  = (int*)(tail + 256);
        wgts   = (float*)(tail + 256 + 262144);
        sel    = (unsigned char*)(tail + 256 + 524288);
        w2g    = (float2*)(tail + 256 + 532480);
        hipMemsetAsync(out, 0, (size_t)out_size * sizeof(float), stream);
    }

    k_pack<<<dim3(8, 16, 16), dim3(256), 0, stream>>>(W1, W2, w1f, w2f);
    k_gate<<<dim3(N_TOK / 32), dim3(256), 0, stream>>>(x, Wg, bg, sel, w2g);
    k_build<<<dim3(N_EXP), dim3(1024), 0, stream>>>(sel, w2g, counts, lists, wgts);
    if (slot) {
        k_experts<true><<<dim3(1024), dim3(512), 0, stream>>>(
            x, w1f, b1, w2f, b2, counts, lists, wgts, ybuf, out);
        k_combine<<<dim3(N_TOK * 64 / 256), dim3(256), 0, stream>>>(ybuf, out);
    } else {
        k_experts<false><<<dim3(1024), dim3(512), 0, stream>>>(
            x, w1f, b1, w2f, b2, counts, lists, wgts, ybuf, out);
    }
}